// Round 1
// baseline (5367.507 us; speedup 1.0000x reference)
//
#include <hip/hip_runtime.h>

// ---- static problem config ----
#define B_ 4
#define Q_ 32
#define D_ 512
#define H_ 8
#define L_ 4
#define P_ 4
#define V_ 12000
#define T_ 16
#define HD_ 64
#define S_ 3840
#define BQ_ 128
#define NSTEP 15

typedef __attribute__((ext_vector_type(8))) short short8;
typedef __attribute__((ext_vector_type(4))) float f32x4;

__device__ inline unsigned short f2bf(float x) {
  union { float f; unsigned u; } v; v.f = x;
  unsigned u = v.u;
  unsigned r = (u + 0x7fffu + ((u >> 16) & 1u)) >> 16;  // RNE
  return (unsigned short)r;
}

__device__ inline float fast_tanh(float x) {
  x = fminf(fmaxf(x, -15.f), 15.f);
  float e = __expf(2.f * x);
  return (e - 1.f) / (e + 1.f);
}
__device__ inline float sigmoidf_(float x) { return 1.f / (1.f + __expf(-x)); }

// ---------------- convert f32 -> bf16 (n4 = n/4) ----------------
__global__ __launch_bounds__(256) void k_f2bf(const float* __restrict__ src,
                                              unsigned short* __restrict__ dst, int n4) {
  int i = blockIdx.x * 256 + threadIdx.x;
  if (i >= n4) return;
  float4 v = ((const float4*)src)[i];
  ushort4 o;
  o.x = f2bf(v.x); o.y = f2bf(v.y); o.z = f2bf(v.z); o.w = f2bf(v.w);
  ((ushort4*)dst)[i] = o;
}

// ---------------- init h0/c0 = 0 ----------------
__global__ __launch_bounds__(256) void k_init(unsigned short* __restrict__ hbf,
                                              float* __restrict__ c) {
  int i = blockIdx.x * 256 + threadIdx.x;  // 65536 total
  hbf[i] = 0;   // bf16 zero
  c[i] = 0.f;
}

// ---------------- MFMA GEMM common pieces ----------------
// Block tile 128(M) x 128(N), BK=32, 256 threads = 4 waves (2x2), wave tile 64x64.
// A: (M,K) bf16 row-major staged to LDS [128][APAD]; B: (N,K) bf16 row-major same.
#define APAD 40  // 32 + 8 shorts pad -> 80B row stride, 16B aligned, spreads banks

__device__ inline void stage_bf(const unsigned short* __restrict__ src, int ldk,
                                unsigned short* dst, int tid) {
#pragma unroll
  for (int i = 0; i < 2; i++) {
    int t = tid + i * 256;
    int r = t >> 2, ko = (t & 3) * 8;
    *(short8*)(dst + r * APAD + ko) = *(const short8*)(src + (size_t)r * ldk + ko);
  }
}

__device__ inline void store_bf8(unsigned short* dst, float4 v0, float4 v1) {
  short8 p;
  p[0] = (short)f2bf(v0.x); p[1] = (short)f2bf(v0.y);
  p[2] = (short)f2bf(v0.z); p[3] = (short)f2bf(v0.w);
  p[4] = (short)f2bf(v1.x); p[5] = (short)f2bf(v1.y);
  p[6] = (short)f2bf(v1.z); p[7] = (short)f2bf(v1.w);
  *(short8*)dst = p;
}

__device__ inline void stage_f32cvt(const float* __restrict__ src, int ldk,
                                    unsigned short* dst, int tid) {
#pragma unroll
  for (int i = 0; i < 2; i++) {
    int t = tid + i * 256;
    int r = t >> 2, ko = (t & 3) * 8;
    const float4* s = (const float4*)(src + (size_t)r * ldk + ko);
    store_bf8(dst + r * APAD + ko, s[0], s[1]);
  }
}

__device__ inline void mfma_step(const unsigned short* As, const unsigned short* Bs,
                                 f32x4 acc[4][4], int wm, int wn, int lane) {
  int r15 = lane & 15, koct = (lane >> 4) * 8;
  short8 a[4], b[4];
#pragma unroll
  for (int mf = 0; mf < 4; mf++)
    a[mf] = *(const short8*)(As + (wm * 64 + mf * 16 + r15) * APAD + koct);
#pragma unroll
  for (int nf = 0; nf < 4; nf++)
    b[nf] = *(const short8*)(Bs + (wn * 64 + nf * 16 + r15) * APAD + koct);
#pragma unroll
  for (int mf = 0; mf < 4; mf++)
#pragma unroll
    for (int nf = 0; nf < 4; nf++)
      acc[mf][nf] = __builtin_amdgcn_mfma_f32_16x16x32_bf16(a[mf], b[nf], acc[mf][nf], 0, 0, 0);
}

// D layout (HW-verified m89): col = lane&15, row = (lane>>4)*4 + j
__device__ inline void mfma_epilogue(float* __restrict__ out, int ldo, int m0, int n0,
                                     int Nmax, const float* __restrict__ bias,
                                     const unsigned char* __restrict__ mask,
                                     f32x4 acc[4][4], int wm, int wn, int lane) {
  int rb = (lane >> 4) * 4, cb = lane & 15;
#pragma unroll
  for (int nf = 0; nf < 4; nf++) {
    int col = n0 + wn * 64 + nf * 16 + cb;
    if (col >= Nmax) continue;
    float bv = bias ? bias[col] : 0.f;
#pragma unroll
    for (int mf = 0; mf < 4; mf++) {
#pragma unroll
      for (int j = 0; j < 4; j++) {
        int row = m0 + wm * 64 + mf * 16 + rb + j;
        float v = acc[mf][nf][j] + bv;
        if (mask && mask[row]) v = 0.f;
        out[(size_t)row * ldo + col] = v;
      }
    }
  }
}

// ---------------- value = enc @ valueW^T + b (masked) ----------------
__global__ __launch_bounds__(256) void k_value_gemm(const float* __restrict__ enc,
    const unsigned short* __restrict__ Wbf, const float* __restrict__ bias,
    const unsigned char* __restrict__ mask, float* __restrict__ out) {
  __shared__ unsigned short As[128 * APAD], Bs[128 * APAD];
  int tid = threadIdx.x;
  int lane = tid & 63, w = tid >> 6, wm = w >> 1, wn = w & 1;
  int m0 = blockIdx.x * 128, n0 = blockIdx.y * 128;
  f32x4 z = {0.f, 0.f, 0.f, 0.f};
  f32x4 acc[4][4];
#pragma unroll
  for (int i = 0; i < 4; i++)
#pragma unroll
    for (int j = 0; j < 4; j++) acc[i][j] = z;
  for (int k0 = 0; k0 < 512; k0 += 32) {
    stage_f32cvt(enc + (size_t)m0 * 512 + k0, 512, As, tid);
    stage_bf(Wbf + (size_t)n0 * 512 + k0, 512, Bs, tid);
    __syncthreads();
    mfma_step(As, Bs, acc, wm, wn, lane);
    __syncthreads();
  }
  mfma_epilogue(out, 512, m0, n0, 512, bias, mask, acc, wm, wn, lane);
}

// ---------------- per-step projections: off, aw (K=1024, A=[h|query]), hproj (K=512, A=h) ----
__global__ __launch_bounds__(256) void k_pre_gemm(const unsigned short* __restrict__ hbf,
    const unsigned short* __restrict__ qbf,
    const unsigned short* __restrict__ offWbf, const float* __restrict__ offb,
    const unsigned short* __restrict__ awWbf, const float* __restrict__ awb,
    const unsigned short* __restrict__ hsWbf, const float* __restrict__ hsb,
    float* __restrict__ offo, float* __restrict__ awo, float* __restrict__ hpo) {
  __shared__ unsigned short As[128 * APAD], Bs[128 * APAD];
  int blk = blockIdx.x;
  const unsigned short* Bw; const float* bias; float* out; int K, n0, ldo;
  if (blk == 0)      { Bw = offWbf; bias = offb; out = offo; K = 1024; n0 = 0; ldo = 128; }
  else if (blk == 1) { Bw = awWbf;  bias = awb;  out = awo;  K = 1024; n0 = 0; ldo = 128; }
  else { Bw = hsWbf; bias = hsb; out = hpo; K = 512; n0 = (blk - 2) * 128; ldo = 512; }
  int tid = threadIdx.x;
  int lane = tid & 63, w = tid >> 6, wm = w >> 1, wn = w & 1;
  f32x4 z = {0.f, 0.f, 0.f, 0.f};
  f32x4 acc[4][4];
#pragma unroll
  for (int i = 0; i < 4; i++)
#pragma unroll
    for (int j = 0; j < 4; j++) acc[i][j] = z;
  for (int k0 = 0; k0 < K; k0 += 32) {
    const unsigned short* Asrc = (k0 < 512) ? (hbf + k0) : (qbf + (k0 - 512));
    stage_bf(Asrc, 512, As, tid);
    stage_bf(Bw + (size_t)n0 * K + k0, K, Bs, tid);
    __syncthreads();
    mfma_step(As, Bs, acc, wm, wn, lane);
    __syncthreads();
  }
  mfma_epilogue(out, ldo, 0, n0, ldo, bias, nullptr, acc, wm, wn, lane);
}

// ---------------- LSTM gates GEMM: M=128, N=2048, K=2048 ----------------
__global__ __launch_bounds__(256) void k_lstm_gemm(const int* __restrict__ seq, int t,
    const float* __restrict__ embedW, const unsigned short* __restrict__ attnbf,
    const unsigned short* __restrict__ qbf, const unsigned short* __restrict__ hbf,
    const unsigned short* __restrict__ Wihbf, const unsigned short* __restrict__ Whhbf,
    float* __restrict__ gates) {
  __shared__ unsigned short As[128 * APAD], Bs[128 * APAD];
  __shared__ int tok_s[128];
  int tid = threadIdx.x;
  if (tid < 128) tok_s[tid] = seq[tid * T_ + t];
  __syncthreads();
  int lane = tid & 63, w = tid >> 6, wm = w >> 1, wn = w & 1;
  int n0 = blockIdx.x * 128;
  f32x4 z = {0.f, 0.f, 0.f, 0.f};
  f32x4 acc[4][4];
#pragma unroll
  for (int i = 0; i < 4; i++)
#pragma unroll
    for (int j = 0; j < 4; j++) acc[i][j] = z;
  for (int k0 = 0; k0 < 2048; k0 += 32) {
    int region = k0 >> 9;
    if (region == 0) {  // embed gather f32 -> bf16
#pragma unroll
      for (int i = 0; i < 2; i++) {
        int tt = tid + i * 256;
        int r = tt >> 2, ko = (tt & 3) * 8;
        const float4* s = (const float4*)(embedW + (size_t)tok_s[r] * 512 + k0 + ko);
        store_bf8(As + r * APAD + ko, s[0], s[1]);
      }
    } else {
      const unsigned short* Asrc = (region == 1) ? (attnbf + (k0 - 512))
                                 : (region == 2) ? (qbf + (k0 - 1024))
                                                 : (hbf + (k0 - 1536));
      stage_bf(Asrc, 512, As, tid);
    }
    if (k0 < 1536) stage_bf(Wihbf + (size_t)n0 * 1536 + k0, 1536, Bs, tid);
    else           stage_bf(Whhbf + (size_t)n0 * 512 + (k0 - 1536), 512, Bs, tid);
    __syncthreads();
    mfma_step(As, Bs, acc, wm, wn, lane);
    __syncthreads();
  }
  mfma_epilogue(gates, 2048, 0, n0, 2048, nullptr, nullptr, acc, wm, wn, lane);
}

// ---------------- logits GEMM: M=128, N=12000, K=512 ----------------
__global__ __launch_bounds__(256) void k_logits_gemm(const unsigned short* __restrict__ hbf,
    const unsigned short* __restrict__ Wbf, const float* __restrict__ bias,
    float* __restrict__ out) {
  __shared__ unsigned short As[128 * APAD], Bs[128 * APAD];
  int tid = threadIdx.x;
  int lane = tid & 63, w = tid >> 6, wm = w >> 1, wn = w & 1;
  int n0 = blockIdx.x * 128;
  f32x4 z = {0.f, 0.f, 0.f, 0.f};
  f32x4 acc[4][4];
#pragma unroll
  for (int i = 0; i < 4; i++)
#pragma unroll
    for (int j = 0; j < 4; j++) acc[i][j] = z;
  for (int k0 = 0; k0 < 512; k0 += 32) {
    stage_bf(hbf + k0, 512, As, tid);
#pragma unroll
    for (int i = 0; i < 2; i++) {  // guarded B stage (N tail)
      int tt = tid + i * 256;
      int r = tt >> 2, ko = (tt & 3) * 8;
      short8 p = {0, 0, 0, 0, 0, 0, 0, 0};
      if (n0 + r < V_) p = *(const short8*)(Wbf + (size_t)(n0 + r) * 512 + k0 + ko);
      *(short8*)(Bs + r * APAD + ko) = p;
    }
    __syncthreads();
    mfma_step(As, Bs, acc, wm, wn, lane);
    __syncthreads();
  }
  mfma_epilogue(out, V_, 0, n0, V_, bias, nullptr, acc, wm, wn, lane);
}

// ---------------- deformable sampling + tanh additive attention ----------------
// one block per (bq, h): 1024 blocks, 256 threads
__global__ __launch_bounds__(256) void k_sample(
    const float* __restrict__ value, const float* __restrict__ offo,
    const float* __restrict__ awo, const float* __restrict__ hproj,
    const float* __restrict__ refp, const float* __restrict__ vrat,
    const float* __restrict__ ctxW, const float* __restrict__ ctxb,
    const float* __restrict__ alphaW, const float* __restrict__ alphab,
    unsigned short* __restrict__ attnbf) {
  __shared__ float ctx_s[16][HD_];
  __shared__ float aw_s[16];
  __shared__ float wgt_s[16];
  __shared__ float hp_s[D_];
  int blk = blockIdx.x;
  int bq = blk >> 3, h = blk & 7;
  int b = bq >> 5;
  int tid = threadIdx.x;

  hp_s[tid] = hproj[bq * D_ + tid];
  hp_s[tid + 256] = hproj[bq * D_ + tid + 256];

  if (tid < 16) {  // aw softmax over the 16 points
    float v = awo[bq * 128 + h * 16 + tid];
    float m = v;
#pragma unroll
    for (int o = 8; o; o >>= 1) m = fmaxf(m, __shfl_xor(m, o, 16));
    float e = __expf(v - m);
    float s = e;
#pragma unroll
    for (int o = 8; o; o >>= 1) s += __shfl_xor(s, o, 16);
    aw_s[tid] = e / s;
  }
  __syncthreads();

  {  // 1-D linear sampling (grid_sample, zero pad), weighted by aw
    const int TSv[4] = {2048, 1024, 512, 256};
    const int LSv[4] = {0, 2048, 3072, 3584};
    float ref = refp[bq];
    int hd = tid & 63;
#pragma unroll
    for (int pp = 0; pp < 4; pp++) {
      int p = pp * 4 + (tid >> 6);
      int l = p >> 2;
      int Tl = TSv[l];
      float off = offo[bq * 128 + h * 16 + p];
      float loc = ref * vrat[b * L_ + l] + off / (float)Tl;
      float x = loc * (float)Tl - 0.5f;
      float x0 = floorf(x);
      float wf = x - x0;
      int i0 = (int)x0;
      const float* vb = value + ((size_t)(b * S_ + LSv[l]) * D_) + h * HD_ + hd;
      float v0 = (i0 >= 0 && i0 < Tl) ? vb[(size_t)i0 * D_] : 0.f;
      float v1 = (i0 + 1 >= 0 && i0 + 1 < Tl) ? vb[(size_t)(i0 + 1) * D_] : 0.f;
      ctx_s[p][hd] = (v0 * (1.f - wf) + v1 * wf) * aw_s[p];
    }
  }
  __syncthreads();

  {  // dot[p] = sum_d alpha[d]*tanh(ctx[p]·ctxW[d] + ctxb[d] + hproj[d])
    int p = tid >> 4, ds = tid & 15;
    float partial = 0.f;
#pragma unroll 4
    for (int j = 0; j < 32; j++) {
      int d = ds + 16 * j;
      const float4* wrow = (const float4*)(ctxW + d * HD_);
      float s = ctxb[d] + hp_s[d];
#pragma unroll
      for (int k4 = 0; k4 < 16; k4++) {
        float4 wv = wrow[k4];
        s += ctx_s[p][k4 * 4 + 0] * wv.x + ctx_s[p][k4 * 4 + 1] * wv.y +
             ctx_s[p][k4 * 4 + 2] * wv.z + ctx_s[p][k4 * 4 + 3] * wv.w;
      }
      partial += alphaW[d] * fast_tanh(s);
    }
#pragma unroll
    for (int o = 8; o; o >>= 1) partial += __shfl_xor(partial, o, 16);
    if (ds == 0) wgt_s[p] = partial + alphab[0];
  }
  __syncthreads();
  if (tid < 16) {  // softmax over 16 points
    float v = wgt_s[tid];
    float m = v;
#pragma unroll
    for (int o = 8; o; o >>= 1) m = fmaxf(m, __shfl_xor(m, o, 16));
    float e = __expf(v - m);
    float s = e;
#pragma unroll
    for (int o = 8; o; o >>= 1) s += __shfl_xor(s, o, 16);
    wgt_s[tid] = e / s;
  }
  __syncthreads();
  if (tid < 64) {  // attn_res = sum_p wgt[p]*ctx[p]
    float a = 0.f;
#pragma unroll
    for (int pi = 0; pi < 16; pi++) a += wgt_s[pi] * ctx_s[pi][tid];
    attnbf[bq * D_ + h * HD_ + tid] = f2bf(a);
  }
}

// ---------------- LSTM cell elementwise ----------------
__global__ __launch_bounds__(256) void k_cell(const float* __restrict__ gates,
    const float* __restrict__ c, float* __restrict__ cn, unsigned short* __restrict__ hbf) {
  int idx = blockIdx.x * 256 + threadIdx.x;  // 65536
  int bq = idx >> 9, d = idx & 511;
  const float* g = gates + (size_t)bq * 2048;
  float gi = g[d], gf = g[512 + d], gg = g[1024 + d], go = g[1536 + d];
  float cc = c[idx];
  float c2 = sigmoidf_(gf) * cc + sigmoidf_(gi) * fast_tanh(gg);
  float h2 = sigmoidf_(go) * fast_tanh(c2);
  cn[idx] = c2;
  hbf[idx] = f2bf(h2);
}

// ---------------- log_softmax rows, write output slice ----------------
__global__ __launch_bounds__(256) void k_lse(const float* __restrict__ logits,
                                             float* __restrict__ out, int t) {
  int row = blockIdx.x, tid = threadIdx.x;
  const float4* lp = (const float4*)(logits + (size_t)row * V_);
  float m = -3.4e38f;
  for (int i = tid; i < V_ / 4; i += 256) {
    float4 v = lp[i];
    m = fmaxf(fmaxf(fmaxf(m, v.x), v.y), fmaxf(v.z, v.w));
  }
  __shared__ float red[4], red2[4];
#pragma unroll
  for (int o = 32; o; o >>= 1) m = fmaxf(m, __shfl_xor(m, o, 64));
  if ((tid & 63) == 0) red[tid >> 6] = m;
  __syncthreads();
  m = fmaxf(fmaxf(red[0], red[1]), fmaxf(red[2], red[3]));
  float s = 0.f;
  for (int i = tid; i < V_ / 4; i += 256) {
    float4 v = lp[i];
    s += __expf(v.x - m) + __expf(v.y - m) + __expf(v.z - m) + __expf(v.w - m);
  }
#pragma unroll
  for (int o = 32; o; o >>= 1) s += __shfl_xor(s, o, 64);
  if ((tid & 63) == 0) red2[tid >> 6] = s;
  __syncthreads();
  s = red2[0] + red2[1] + red2[2] + red2[3];
  float lse = m + __logf(s);
  float4* op = (float4*)(out + ((size_t)row * (T_ - 1) + t) * V_);
  for (int i = tid; i < V_ / 4; i += 256) {
    float4 v = lp[i];
    v.x -= lse; v.y -= lse; v.z -= lse; v.w -= lse;
    op[i] = v;
  }
}

// ---------------- host launch ----------------
extern "C" void kernel_launch(void* const* d_in, const int* in_sizes, int n_in,
                              void* d_out, int out_size, void* d_ws, size_t ws_size,
                              hipStream_t stream) {
  const int* seq             = (const int*)d_in[0];
  const float* query         = (const float*)d_in[1];
  const float* refp          = (const float*)d_in[2];
  const float* enc           = (const float*)d_in[3];
  const float* vrat          = (const float*)d_in[4];
  const unsigned char* mask  = (const unsigned char*)d_in[5];
  const float* embedW        = (const float*)d_in[8];
  const float* logitW        = (const float*)d_in[9];
  const float* logitb        = (const float*)d_in[10];
  const float* Wih           = (const float*)d_in[11];
  const float* Whh           = (const float*)d_in[12];
  const float* valueW        = (const float*)d_in[13];
  const float* valueb        = (const float*)d_in[14];
  const float* offW          = (const float*)d_in[15];
  const float* offb          = (const float*)d_in[16];
  const float* awW           = (const float*)d_in[17];
  const float* awb           = (const float*)d_in[18];
  const float* ctxW          = (const float*)d_in[19];
  const float* ctxb          = (const float*)d_in[20];
  const float* alphaW        = (const float*)d_in[21 + 2];  // careful below
  // NOTE: correct order is ctx_W(19), ctx_b(20), hs_W(21), hs_b(22), alpha_W(23), alpha_b(24)
  const float* hsW           = (const float*)d_in[21];
  const float* hsb           = (const float*)d_in[22];
  alphaW                     = (const float*)d_in[23];
  const float* alphab        = (const float*)d_in[24];

  char* wp = (char*)d_ws;
  auto alloc_f = [&](size_t n) { float* p = (float*)wp; wp += ((n * 4 + 255) / 256) * 256; return p; };
  auto alloc_u = [&](size_t n) { unsigned short* p = (unsigned short*)wp; wp += ((n * 2 + 255) / 256) * 256; return p; };

  float* value   = alloc_f((size_t)B_ * S_ * D_);   // 7,864,320
  float* logits  = alloc_f((size_t)BQ_ * V_);       // 1,536,000
  float* gates   = alloc_f((size_t)BQ_ * 2048);
  float* hproj   = alloc_f((size_t)BQ_ * D_);
  float* offo    = alloc_f((size_t)BQ_ * 128);
  float* awo     = alloc_f((size_t)BQ_ * 128);
  float* c0      = alloc_f((size_t)BQ_ * D_);
  float* c1      = alloc_f((size_t)BQ_ * D_);
  unsigned short* hbf0    = alloc_u((size_t)BQ_ * D_);
  unsigned short* hbf1    = alloc_u((size_t)BQ_ * D_);
  unsigned short* attnbf  = alloc_u((size_t)BQ_ * D_);
  unsigned short* qbf     = alloc_u((size_t)BQ_ * D_);
  unsigned short* logitWbf = alloc_u((size_t)V_ * D_);      // 6,144,000
  unsigned short* Wihbf    = alloc_u((size_t)2048 * 1536);  // 3,145,728
  unsigned short* Whhbf    = alloc_u((size_t)2048 * 512);
  unsigned short* offWbf   = alloc_u((size_t)128 * 1024);
  unsigned short* awWbf    = alloc_u((size_t)128 * 1024);
  unsigned short* hsWbf    = alloc_u((size_t)512 * 512);
  unsigned short* valueWbf = alloc_u((size_t)512 * 512);

  // one-time converts + init
  k_init<<<256, 256, 0, stream>>>(hbf0, c0);
  k_f2bf<<<6000, 256, 0, stream>>>(logitW, logitWbf, 1536000);
  k_f2bf<<<3072, 256, 0, stream>>>(Wih, Wihbf, 786432);
  k_f2bf<<<1024, 256, 0, stream>>>(Whh, Whhbf, 262144);
  k_f2bf<<<128, 256, 0, stream>>>(offW, offWbf, 32768);
  k_f2bf<<<128, 256, 0, stream>>>(awW, awWbf, 32768);
  k_f2bf<<<256, 256, 0, stream>>>(hsW, hsWbf, 65536);
  k_f2bf<<<256, 256, 0, stream>>>(valueW, valueWbf, 65536);
  k_f2bf<<<64, 256, 0, stream>>>(query, qbf, 16384);

  k_value_gemm<<<dim3(120, 4), 256, 0, stream>>>(enc, valueWbf, valueb, mask, value);

  unsigned short* hb[2] = {hbf0, hbf1};
  float* cb[2] = {c0, c1};
  float* outp = (float*)d_out;

  for (int t = 0; t < NSTEP; t++) {
    int cur = t & 1, nxt = cur ^ 1;
    k_pre_gemm<<<6, 256, 0, stream>>>(hb[cur], qbf, offWbf, offb, awWbf, awb,
                                      hsWbf, hsb, offo, awo, hproj);
    k_sample<<<1024, 256, 0, stream>>>(value, offo, awo, hproj, refp, vrat,
                                       ctxW, ctxb, alphaW, alphab, attnbf);
    k_lstm_gemm<<<16, 256, 0, stream>>>(seq, t, embedW, attnbf, qbf, hb[cur],
                                        Wihbf, Whhbf, gates);
    k_cell<<<256, 256, 0, stream>>>(gates, cb[cur], cb[nxt], hb[nxt]);
    k_logits_gemm<<<94, 256, 0, stream>>>(hb[nxt], logitWbf, logitb, logits);
    k_lse<<<128, 256, 0, stream>>>(logits, outp, t);
  }
}

// Round 2
// 2352.178 us; speedup vs baseline: 2.2819x; 2.2819x over previous
//
#include <hip/hip_runtime.h>

// ---- static problem config ----
#define B_ 4
#define Q_ 32
#define D_ 512
#define H_ 8
#define L_ 4
#define P_ 4
#define V_ 12000
#define T_ 16
#define HD_ 64
#define S_ 3840
#define BQ_ 128
#define NSTEP 15

typedef __attribute__((ext_vector_type(8))) short short8;
typedef __attribute__((ext_vector_type(4))) float f32x4;

__device__ inline unsigned short f2bf(float x) {
  union { float f; unsigned u; } v; v.f = x;
  unsigned u = v.u;
  unsigned r = (u + 0x7fffu + ((u >> 16) & 1u)) >> 16;  // RNE
  return (unsigned short)r;
}

__device__ inline float fast_tanh(float x) {
  x = fminf(fmaxf(x, -15.f), 15.f);
  float e = __expf(2.f * x);
  return (e - 1.f) / (e + 1.f);
}
__device__ inline float sigmoidf_(float x) { return 1.f / (1.f + __expf(-x)); }

// ---------------- convert f32 -> bf16 (n4 = n/4) ----------------
__global__ __launch_bounds__(256) void k_f2bf(const float* __restrict__ src,
                                              unsigned short* __restrict__ dst, int n4) {
  int i = blockIdx.x * 256 + threadIdx.x;
  if (i >= n4) return;
  float4 v = ((const float4*)src)[i];
  ushort4 o;
  o.x = f2bf(v.x); o.y = f2bf(v.y); o.z = f2bf(v.z); o.w = f2bf(v.w);
  ((ushort4*)dst)[i] = o;
}

// ---------------- transpose ctxW (512,64) -> ctxWT (64,512) ----------------
__global__ __launch_bounds__(256) void k_transpose_ctxW(const float* __restrict__ ctxW,
                                                        float* __restrict__ ctxWT) {
  // 64 blocks: block = k, threads cover d (2 each)
  int k = blockIdx.x;
#pragma unroll
  for (int i = 0; i < 2; i++) {
    int d = threadIdx.x + i * 256;
    ctxWT[k * 512 + d] = ctxW[d * 64 + k];
  }
}

// ---------------- init h0/c0 = 0 ----------------
__global__ __launch_bounds__(256) void k_init(unsigned short* __restrict__ hbf,
                                              float* __restrict__ c) {
  int i = blockIdx.x * 256 + threadIdx.x;  // 65536 total
  hbf[i] = 0;   // bf16 zero
  c[i] = 0.f;
}

// ---------------- MFMA GEMM common pieces ----------------
#define APAD 40

__device__ inline void stage_bf(const unsigned short* __restrict__ src, int ldk,
                                unsigned short* dst, int tid) {
#pragma unroll
  for (int i = 0; i < 2; i++) {
    int t = tid + i * 256;
    int r = t >> 2, ko = (t & 3) * 8;
    *(short8*)(dst + r * APAD + ko) = *(const short8*)(src + (size_t)r * ldk + ko);
  }
}

__device__ inline void store_bf8(unsigned short* dst, float4 v0, float4 v1) {
  short8 p;
  p[0] = (short)f2bf(v0.x); p[1] = (short)f2bf(v0.y);
  p[2] = (short)f2bf(v0.z); p[3] = (short)f2bf(v0.w);
  p[4] = (short)f2bf(v1.x); p[5] = (short)f2bf(v1.y);
  p[6] = (short)f2bf(v1.z); p[7] = (short)f2bf(v1.w);
  *(short8*)dst = p;
}

__device__ inline void stage_f32cvt(const float* __restrict__ src, int ldk,
                                    unsigned short* dst, int tid) {
#pragma unroll
  for (int i = 0; i < 2; i++) {
    int t = tid + i * 256;
    int r = t >> 2, ko = (t & 3) * 8;
    const float4* s = (const float4*)(src + (size_t)r * ldk + ko);
    store_bf8(dst + r * APAD + ko, s[0], s[1]);
  }
}

__device__ inline void mfma_step(const unsigned short* As, const unsigned short* Bs,
                                 f32x4 acc[4][4], int wm, int wn, int lane) {
  int r15 = lane & 15, koct = (lane >> 4) * 8;
  short8 a[4], b[4];
#pragma unroll
  for (int mf = 0; mf < 4; mf++)
    a[mf] = *(const short8*)(As + (wm * 64 + mf * 16 + r15) * APAD + koct);
#pragma unroll
  for (int nf = 0; nf < 4; nf++)
    b[nf] = *(const short8*)(Bs + (wn * 64 + nf * 16 + r15) * APAD + koct);
#pragma unroll
  for (int mf = 0; mf < 4; mf++)
#pragma unroll
    for (int nf = 0; nf < 4; nf++)
      acc[mf][nf] = __builtin_amdgcn_mfma_f32_16x16x32_bf16(a[mf], b[nf], acc[mf][nf], 0, 0, 0);
}

__device__ inline void mfma_epilogue(float* __restrict__ out, int ldo, int m0, int n0,
                                     int Nmax, const float* __restrict__ bias,
                                     const unsigned char* __restrict__ mask,
                                     f32x4 acc[4][4], int wm, int wn, int lane) {
  int rb = (lane >> 4) * 4, cb = lane & 15;
#pragma unroll
  for (int nf = 0; nf < 4; nf++) {
    int col = n0 + wn * 64 + nf * 16 + cb;
    if (col >= Nmax) continue;
    float bv = bias ? bias[col] : 0.f;
#pragma unroll
    for (int mf = 0; mf < 4; mf++) {
#pragma unroll
      for (int j = 0; j < 4; j++) {
        int row = m0 + wm * 64 + mf * 16 + rb + j;
        float v = acc[mf][nf][j] + bv;
        if (mask && mask[row]) v = 0.f;
        out[(size_t)row * ldo + col] = v;
      }
    }
  }
}

// ---------------- value = enc @ valueW^T + b (masked) ----------------
__global__ __launch_bounds__(256) void k_value_gemm(const float* __restrict__ enc,
    const unsigned short* __restrict__ Wbf, const float* __restrict__ bias,
    const unsigned char* __restrict__ mask, float* __restrict__ out) {
  __shared__ unsigned short As[128 * APAD], Bs[128 * APAD];
  int tid = threadIdx.x;
  int lane = tid & 63, w = tid >> 6, wm = w >> 1, wn = w & 1;
  int m0 = blockIdx.x * 128, n0 = blockIdx.y * 128;
  f32x4 z = {0.f, 0.f, 0.f, 0.f};
  f32x4 acc[4][4];
#pragma unroll
  for (int i = 0; i < 4; i++)
#pragma unroll
    for (int j = 0; j < 4; j++) acc[i][j] = z;
  for (int k0 = 0; k0 < 512; k0 += 32) {
    stage_f32cvt(enc + (size_t)m0 * 512 + k0, 512, As, tid);
    stage_bf(Wbf + (size_t)n0 * 512 + k0, 512, Bs, tid);
    __syncthreads();
    mfma_step(As, Bs, acc, wm, wn, lane);
    __syncthreads();
  }
  mfma_epilogue(out, 512, m0, n0, 512, bias, mask, acc, wm, wn, lane);
}

// ---------------- per-step projections ----------------
__global__ __launch_bounds__(256) void k_pre_gemm(const unsigned short* __restrict__ hbf,
    const unsigned short* __restrict__ qbf,
    const unsigned short* __restrict__ offWbf, const float* __restrict__ offb,
    const unsigned short* __restrict__ awWbf, const float* __restrict__ awb,
    const unsigned short* __restrict__ hsWbf, const float* __restrict__ hsb,
    float* __restrict__ offo, float* __restrict__ awo, float* __restrict__ hpo) {
  __shared__ unsigned short As[128 * APAD], Bs[128 * APAD];
  int blk = blockIdx.x;
  const unsigned short* Bw; const float* bias; float* out; int K, n0, ldo;
  if (blk == 0)      { Bw = offWbf; bias = offb; out = offo; K = 1024; n0 = 0; ldo = 128; }
  else if (blk == 1) { Bw = awWbf;  bias = awb;  out = awo;  K = 1024; n0 = 0; ldo = 128; }
  else { Bw = hsWbf; bias = hsb; out = hpo; K = 512; n0 = (blk - 2) * 128; ldo = 512; }
  int tid = threadIdx.x;
  int lane = tid & 63, w = tid >> 6, wm = w >> 1, wn = w & 1;
  f32x4 z = {0.f, 0.f, 0.f, 0.f};
  f32x4 acc[4][4];
#pragma unroll
  for (int i = 0; i < 4; i++)
#pragma unroll
    for (int j = 0; j < 4; j++) acc[i][j] = z;
  for (int k0 = 0; k0 < K; k0 += 32) {
    const unsigned short* Asrc = (k0 < 512) ? (hbf + k0) : (qbf + (k0 - 512));
    stage_bf(Asrc, 512, As, tid);
    stage_bf(Bw + (size_t)n0 * K + k0, K, Bs, tid);
    __syncthreads();
    mfma_step(As, Bs, acc, wm, wn, lane);
    __syncthreads();
  }
  mfma_epilogue(out, ldo, 0, n0, ldo, bias, nullptr, acc, wm, wn, lane);
}

// ---------------- LSTM gates GEMM: M=128, N=2048, K=2048 ----------------
__global__ __launch_bounds__(256) void k_lstm_gemm(const int* __restrict__ seq, int t,
    const float* __restrict__ embedW, const unsigned short* __restrict__ attnbf,
    const unsigned short* __restrict__ qbf, const unsigned short* __restrict__ hbf,
    const unsigned short* __restrict__ Wihbf, const unsigned short* __restrict__ Whhbf,
    float* __restrict__ gates) {
  __shared__ unsigned short As[128 * APAD], Bs[128 * APAD];
  __shared__ int tok_s[128];
  int tid = threadIdx.x;
  if (tid < 128) tok_s[tid] = seq[tid * T_ + t];
  __syncthreads();
  int lane = tid & 63, w = tid >> 6, wm = w >> 1, wn = w & 1;
  int n0 = blockIdx.x * 128;
  f32x4 z = {0.f, 0.f, 0.f, 0.f};
  f32x4 acc[4][4];
#pragma unroll
  for (int i = 0; i < 4; i++)
#pragma unroll
    for (int j = 0; j < 4; j++) acc[i][j] = z;
  for (int k0 = 0; k0 < 2048; k0 += 32) {
    int region = k0 >> 9;
    if (region == 0) {
#pragma unroll
      for (int i = 0; i < 2; i++) {
        int tt = tid + i * 256;
        int r = tt >> 2, ko = (tt & 3) * 8;
        const float4* s = (const float4*)(embedW + (size_t)tok_s[r] * 512 + k0 + ko);
        store_bf8(As + r * APAD + ko, s[0], s[1]);
      }
    } else {
      const unsigned short* Asrc = (region == 1) ? (attnbf + (k0 - 512))
                                 : (region == 2) ? (qbf + (k0 - 1024))
                                                 : (hbf + (k0 - 1536));
      stage_bf(Asrc, 512, As, tid);
    }
    if (k0 < 1536) stage_bf(Wihbf + (size_t)n0 * 1536 + k0, 1536, Bs, tid);
    else           stage_bf(Whhbf + (size_t)n0 * 512 + (k0 - 1536), 512, Bs, tid);
    __syncthreads();
    mfma_step(As, Bs, acc, wm, wn, lane);
    __syncthreads();
  }
  mfma_epilogue(gates, 2048, 0, n0, 2048, nullptr, nullptr, acc, wm, wn, lane);
}

// ---------------- logits GEMM: M=128, N=12000, K=512 ----------------
__global__ __launch_bounds__(256) void k_logits_gemm(const unsigned short* __restrict__ hbf,
    const unsigned short* __restrict__ Wbf, const float* __restrict__ bias,
    float* __restrict__ out) {
  __shared__ unsigned short As[128 * APAD], Bs[128 * APAD];
  int tid = threadIdx.x;
  int lane = tid & 63, w = tid >> 6, wm = w >> 1, wn = w & 1;
  int n0 = blockIdx.x * 128;
  f32x4 z = {0.f, 0.f, 0.f, 0.f};
  f32x4 acc[4][4];
#pragma unroll
  for (int i = 0; i < 4; i++)
#pragma unroll
    for (int j = 0; j < 4; j++) acc[i][j] = z;
  for (int k0 = 0; k0 < 512; k0 += 32) {
    stage_bf(hbf + k0, 512, As, tid);
#pragma unroll
    for (int i = 0; i < 2; i++) {
      int tt = tid + i * 256;
      int r = tt >> 2, ko = (tt & 3) * 8;
      short8 p = {0, 0, 0, 0, 0, 0, 0, 0};
      if (n0 + r < V_) p = *(const short8*)(Wbf + (size_t)(n0 + r) * 512 + k0 + ko);
      *(short8*)(Bs + r * APAD + ko) = p;
    }
    __syncthreads();
    mfma_step(As, Bs, acc, wm, wn, lane);
    __syncthreads();
  }
  mfma_epilogue(out, V_, 0, n0, V_, bias, nullptr, acc, wm, wn, lane);
}

// ---------------- deformable sampling + tanh additive attention ----------------
// one block per (bq, h): 1024 blocks, 256 threads
// Phase B restructured: d is the lane axis (coalesced ctxWT loads, broadcast LDS reads)
__global__ __launch_bounds__(256) void k_sample(
    const float* __restrict__ value, const float* __restrict__ offo,
    const float* __restrict__ awo, const float* __restrict__ hproj,
    const float* __restrict__ refp, const float* __restrict__ vrat,
    const float* __restrict__ ctxWT, const float* __restrict__ ctxb,
    const float* __restrict__ alphaW, const float* __restrict__ alphab,
    unsigned short* __restrict__ attnbf) {
  __shared__ float ctx_s[16][HD_];
  __shared__ float aw_s[16];
  __shared__ float wgt_s[16];
  __shared__ float wred[4][16];
  int blk = blockIdx.x;
  int bq = blk >> 3, h = blk & 7;
  int b = bq >> 5;
  int tid = threadIdx.x;
  int lane = tid & 63, wid = tid >> 6;

  if (tid < 16) {  // aw softmax over the 16 points
    float v = awo[bq * 128 + h * 16 + tid];
    float m = v;
#pragma unroll
    for (int o = 8; o; o >>= 1) m = fmaxf(m, __shfl_xor(m, o, 16));
    float e = __expf(v - m);
    float s = e;
#pragma unroll
    for (int o = 8; o; o >>= 1) s += __shfl_xor(s, o, 16);
    aw_s[tid] = e / s;
  }
  __syncthreads();

  {  // Phase A: 1-D linear sampling (grid_sample, zero pad), weighted by aw
    const int TSv[4] = {2048, 1024, 512, 256};
    const int LSv[4] = {0, 2048, 3072, 3584};
    float ref = refp[bq];
    int hd = tid & 63;
#pragma unroll
    for (int pp = 0; pp < 4; pp++) {
      int p = pp * 4 + (tid >> 6);
      int l = p >> 2;
      int Tl = TSv[l];
      float off = offo[bq * 128 + h * 16 + p];
      float loc = ref * vrat[b * L_ + l] + off / (float)Tl;
      float x = loc * (float)Tl - 0.5f;
      float x0 = floorf(x);
      float wf = x - x0;
      int i0 = (int)x0;
      const float* vb = value + ((size_t)(b * S_ + LSv[l]) * D_) + h * HD_ + hd;
      float v0 = (i0 >= 0 && i0 < Tl) ? vb[(size_t)i0 * D_] : 0.f;
      float v1 = (i0 + 1 >= 0 && i0 + 1 < Tl) ? vb[(size_t)(i0 + 1) * D_] : 0.f;
      ctx_s[p][hd] = (v0 * (1.f - wf) + v1 * wf) * aw_s[p];
    }
  }
  __syncthreads();

  // Phase B: s[p][d0..d1] = ctx[p] . ctxWT[:, d], d0=2*tid, d1=2*tid+1 (coalesced)
  float2 sacc[16];
#pragma unroll
  for (int p = 0; p < 16; p++) { sacc[p].x = 0.f; sacc[p].y = 0.f; }
  for (int k4 = 0; k4 < 16; k4++) {
    float2 wv[4];
#pragma unroll
    for (int kk = 0; kk < 4; kk++)
      wv[kk] = *(const float2*)(ctxWT + (k4 * 4 + kk) * 512 + 2 * tid);
#pragma unroll
    for (int p = 0; p < 16; p++) {
      float4 c = *(const float4*)(&ctx_s[p][k4 * 4]);
      sacc[p].x += c.x * wv[0].x + c.y * wv[1].x + c.z * wv[2].x + c.w * wv[3].x;
      sacc[p].y += c.x * wv[0].y + c.y * wv[1].y + c.z * wv[2].y + c.w * wv[3].y;
    }
  }

  // Phase C: part[p] = alpha[d0]*tanh(s.x+cb+hp) + alpha[d1]*tanh(s.y+cb+hp); reduce over d
  {
    float2 cb = *(const float2*)(ctxb + 2 * tid);
    float2 hp = *(const float2*)(hproj + bq * D_ + 2 * tid);
    float2 al = *(const float2*)(alphaW + 2 * tid);
    float part[16];
#pragma unroll
    for (int p = 0; p < 16; p++)
      part[p] = al.x * fast_tanh(sacc[p].x + cb.x + hp.x) +
                al.y * fast_tanh(sacc[p].y + cb.y + hp.y);
#pragma unroll
    for (int o = 32; o; o >>= 1)
#pragma unroll
      for (int p = 0; p < 16; p++) part[p] += __shfl_xor(part[p], o, 64);
    if (lane == 0)
#pragma unroll
      for (int p = 0; p < 16; p++) wred[wid][p] = part[p];
  }
  __syncthreads();
  if (tid < 16) {  // finish reduce + softmax over 16 points
    float v = wred[0][tid] + wred[1][tid] + wred[2][tid] + wred[3][tid] + alphab[0];
    float m = v;
#pragma unroll
    for (int o = 8; o; o >>= 1) m = fmaxf(m, __shfl_xor(m, o, 16));
    float e = __expf(v - m);
    float s = e;
#pragma unroll
    for (int o = 8; o; o >>= 1) s += __shfl_xor(s, o, 16);
    wgt_s[tid] = e / s;
  }
  __syncthreads();
  if (tid < 64) {  // attn_res = sum_p wgt[p]*ctx[p]
    float a = 0.f;
#pragma unroll
    for (int pi = 0; pi < 16; pi++) a += wgt_s[pi] * ctx_s[pi][tid];
    attnbf[bq * D_ + h * HD_ + tid] = f2bf(a);
  }
}

// ---------------- LSTM cell elementwise ----------------
__global__ __launch_bounds__(256) void k_cell(const float* __restrict__ gates,
    const float* __restrict__ c, float* __restrict__ cn, unsigned short* __restrict__ hbf) {
  int idx = blockIdx.x * 256 + threadIdx.x;  // 65536
  int bq = idx >> 9, d = idx & 511;
  const float* g = gates + (size_t)bq * 2048;
  float gi = g[d], gf = g[512 + d], gg = g[1024 + d], go = g[1536 + d];
  float cc = c[idx];
  float c2 = sigmoidf_(gf) * cc + sigmoidf_(gi) * fast_tanh(gg);
  float h2 = sigmoidf_(go) * fast_tanh(c2);
  cn[idx] = c2;
  hbf[idx] = f2bf(h2);
}

// ---------------- log_softmax rows, write output slice ----------------
__global__ __launch_bounds__(256) void k_lse(const float* __restrict__ logits,
                                             float* __restrict__ out, int t) {
  int row = blockIdx.x, tid = threadIdx.x;
  const float4* lp = (const float4*)(logits + (size_t)row * V_);
  float m = -3.4e38f;
  for (int i = tid; i < V_ / 4; i += 256) {
    float4 v = lp[i];
    m = fmaxf(fmaxf(fmaxf(m, v.x), v.y), fmaxf(v.z, v.w));
  }
  __shared__ float red[4], red2[4];
#pragma unroll
  for (int o = 32; o; o >>= 1) m = fmaxf(m, __shfl_xor(m, o, 64));
  if ((tid & 63) == 0) red[tid >> 6] = m;
  __syncthreads();
  m = fmaxf(fmaxf(red[0], red[1]), fmaxf(red[2], red[3]));
  float s = 0.f;
  for (int i = tid; i < V_ / 4; i += 256) {
    float4 v = lp[i];
    s += __expf(v.x - m) + __expf(v.y - m) + __expf(v.z - m) + __expf(v.w - m);
  }
#pragma unroll
  for (int o = 32; o; o >>= 1) s += __shfl_xor(s, o, 64);
  if ((tid & 63) == 0) red2[tid >> 6] = s;
  __syncthreads();
  s = red2[0] + red2[1] + red2[2] + red2[3];
  float lse = m + __logf(s);
  float4* op = (float4*)(out + ((size_t)row * (T_ - 1) + t) * V_);
  for (int i = tid; i < V_ / 4; i += 256) {
    float4 v = lp[i];
    v.x -= lse; v.y -= lse; v.z -= lse; v.w -= lse;
    op[i] = v;
  }
}

// ---------------- host launch ----------------
extern "C" void kernel_launch(void* const* d_in, const int* in_sizes, int n_in,
                              void* d_out, int out_size, void* d_ws, size_t ws_size,
                              hipStream_t stream) {
  const int* seq             = (const int*)d_in[0];
  const float* query         = (const float*)d_in[1];
  const float* refp          = (const float*)d_in[2];
  const float* enc           = (const float*)d_in[3];
  const float* vrat          = (const float*)d_in[4];
  const unsigned char* mask  = (const unsigned char*)d_in[5];
  const float* embedW        = (const float*)d_in[8];
  const float* logitW        = (const float*)d_in[9];
  const float* logitb        = (const float*)d_in[10];
  const float* Wih           = (const float*)d_in[11];
  const float* Whh           = (const float*)d_in[12];
  const float* valueW        = (const float*)d_in[13];
  const float* valueb        = (const float*)d_in[14];
  const float* offW          = (const float*)d_in[15];
  const float* offb          = (const float*)d_in[16];
  const float* awW           = (const float*)d_in[17];
  const float* awb           = (const float*)d_in[18];
  const float* ctxW          = (const float*)d_in[19];
  const float* ctxb          = (const float*)d_in[20];
  const float* hsW           = (const float*)d_in[21];
  const float* hsb           = (const float*)d_in[22];
  const float* alphaW        = (const float*)d_in[23];
  const float* alphab        = (const float*)d_in[24];

  char* wp = (char*)d_ws;
  auto alloc_f = [&](size_t n) { float* p = (float*)wp; wp += ((n * 4 + 255) / 256) * 256; return p; };
  auto alloc_u = [&](size_t n) { unsigned short* p = (unsigned short*)wp; wp += ((n * 2 + 255) / 256) * 256; return p; };

  float* value   = alloc_f((size_t)B_ * S_ * D_);
  float* logits  = alloc_f((size_t)BQ_ * V_);
  float* gates   = alloc_f((size_t)BQ_ * 2048);
  float* hproj   = alloc_f((size_t)BQ_ * D_);
  float* offo    = alloc_f((size_t)BQ_ * 128);
  float* awo     = alloc_f((size_t)BQ_ * 128);
  float* c0      = alloc_f((size_t)BQ_ * D_);
  float* c1      = alloc_f((size_t)BQ_ * D_);
  float* ctxWT   = alloc_f((size_t)64 * 512);
  unsigned short* hbf0    = alloc_u((size_t)BQ_ * D_);
  unsigned short* hbf1    = alloc_u((size_t)BQ_ * D_);
  unsigned short* attnbf  = alloc_u((size_t)BQ_ * D_);
  unsigned short* qbf     = alloc_u((size_t)BQ_ * D_);
  unsigned short* logitWbf = alloc_u((size_t)V_ * D_);
  unsigned short* Wihbf    = alloc_u((size_t)2048 * 1536);
  unsigned short* Whhbf    = alloc_u((size_t)2048 * 512);
  unsigned short* offWbf   = alloc_u((size_t)128 * 1024);
  unsigned short* awWbf    = alloc_u((size_t)128 * 1024);
  unsigned short* hsWbf    = alloc_u((size_t)512 * 512);
  unsigned short* valueWbf = alloc_u((size_t)512 * 512);

  // one-time converts + init
  k_init<<<256, 256, 0, stream>>>(hbf0, c0);
  k_f2bf<<<6000, 256, 0, stream>>>(logitW, logitWbf, 1536000);
  k_f2bf<<<3072, 256, 0, stream>>>(Wih, Wihbf, 786432);
  k_f2bf<<<1024, 256, 0, stream>>>(Whh, Whhbf, 262144);
  k_f2bf<<<128, 256, 0, stream>>>(offW, offWbf, 32768);
  k_f2bf<<<128, 256, 0, stream>>>(awW, awWbf, 32768);
  k_f2bf<<<256, 256, 0, stream>>>(hsW, hsWbf, 65536);
  k_f2bf<<<256, 256, 0, stream>>>(valueW, valueWbf, 65536);
  k_f2bf<<<64, 256, 0, stream>>>(query, qbf, 16384);
  k_transpose_ctxW<<<64, 256, 0, stream>>>(ctxW, ctxWT);

  k_value_gemm<<<dim3(120, 4), 256, 0, stream>>>(enc, valueWbf, valueb, mask, value);

  unsigned short* hb[2] = {hbf0, hbf1};
  float* cb[2] = {c0, c1};
  float* outp = (float*)d_out;

  for (int t = 0; t < NSTEP; t++) {
    int cur = t & 1, nxt = cur ^ 1;
    k_pre_gemm<<<6, 256, 0, stream>>>(hb[cur], qbf, offWbf, offb, awWbf, awb,
                                      hsWbf, hsb, offo, awo, hproj);
    k_sample<<<1024, 256, 0, stream>>>(value, offo, awo, hproj, refp, vrat,
                                       ctxWT, ctxb, alphaW, alphab, attnbf);
    k_lstm_gemm<<<16, 256, 0, stream>>>(seq, t, embedW, attnbf, qbf, hb[cur],
                                        Wihbf, Whhbf, gates);
    k_cell<<<256, 256, 0, stream>>>(gates, cb[cur], cb[nxt], hb[nxt]);
    k_logits_gemm<<<94, 256, 0, stream>>>(hb[nxt], logitWbf, logitb, logits);
    k_lse<<<128, 256, 0, stream>>>(logits, outp, t);
  }
}

// Round 3
// 1509.931 us; speedup vs baseline: 3.5548x; 1.5578x over previous
//
#include <hip/hip_runtime.h>

// ---- static problem config ----
#define B_ 4
#define Q_ 32
#define D_ 512
#define H_ 8
#define L_ 4
#define P_ 4
#define V_ 12000
#define T_ 16
#define HD_ 64
#define S_ 3840
#define BQ_ 128
#define NSTEP 15

typedef __attribute__((ext_vector_type(8))) short short8;
typedef __attribute__((ext_vector_type(4))) float f32x4;

__device__ inline unsigned short f2bf(float x) {
  union { float f; unsigned u; } v; v.f = x;
  unsigned u = v.u;
  unsigned r = (u + 0x7fffu + ((u >> 16) & 1u)) >> 16;  // RNE
  return (unsigned short)r;
}
__device__ inline float bf2f(unsigned short b) {
  union { unsigned u; float f; } v; v.u = ((unsigned)b) << 16; return v.f;
}

__device__ inline float fast_tanh(float x) {
  x = fminf(fmaxf(x, -15.f), 15.f);
  float e = __expf(2.f * x);
  return (e - 1.f) / (e + 1.f);
}
__device__ inline float sigmoidf_(float x) { return 1.f / (1.f + __expf(-x)); }

// ---------------- convert f32 -> bf16 (n4 = n/4) ----------------
__global__ __launch_bounds__(256) void k_f2bf(const float* __restrict__ src,
                                              unsigned short* __restrict__ dst, int n4) {
  int i = blockIdx.x * 256 + threadIdx.x;
  if (i >= n4) return;
  float4 v = ((const float4*)src)[i];
  ushort4 o;
  o.x = f2bf(v.x); o.y = f2bf(v.y); o.z = f2bf(v.z); o.w = f2bf(v.w);
  ((ushort4*)dst)[i] = o;
}

// ---------------- transpose ctxW (512,64) -> ctxWT (64,512) ----------------
__global__ __launch_bounds__(256) void k_transpose_ctxW(const float* __restrict__ ctxW,
                                                        float* __restrict__ ctxWT) {
  int k = blockIdx.x;
#pragma unroll
  for (int i = 0; i < 2; i++) {
    int d = threadIdx.x + i * 256;
    ctxWT[k * 512 + d] = ctxW[d * 64 + k];
  }
}

// ---------------- init h0/c0 = 0 ----------------
__global__ __launch_bounds__(256) void k_init(unsigned short* __restrict__ hbf,
                                              float* __restrict__ c) {
  int i = blockIdx.x * 256 + threadIdx.x;  // 65536 total
  hbf[i] = 0;
  c[i] = 0.f;
}

// ---------------- MFMA GEMM common pieces ----------------
#define APAD 40

__device__ inline void stage_bf(const unsigned short* __restrict__ src, int ldk,
                                unsigned short* dst, int tid) {
#pragma unroll
  for (int i = 0; i < 2; i++) {
    int t = tid + i * 256;
    int r = t >> 2, ko = (t & 3) * 8;
    *(short8*)(dst + r * APAD + ko) = *(const short8*)(src + (size_t)r * ldk + ko);
  }
}

__device__ inline void store_bf8(unsigned short* dst, float4 v0, float4 v1) {
  short8 p;
  p[0] = (short)f2bf(v0.x); p[1] = (short)f2bf(v0.y);
  p[2] = (short)f2bf(v0.z); p[3] = (short)f2bf(v0.w);
  p[4] = (short)f2bf(v1.x); p[5] = (short)f2bf(v1.y);
  p[6] = (short)f2bf(v1.z); p[7] = (short)f2bf(v1.w);
  *(short8*)dst = p;
}

__device__ inline void stage_f32cvt(const float* __restrict__ src, int ldk,
                                    unsigned short* dst, int tid) {
#pragma unroll
  for (int i = 0; i < 2; i++) {
    int t = tid + i * 256;
    int r = t >> 2, ko = (t & 3) * 8;
    const float4* s = (const float4*)(src + (size_t)r * ldk + ko);
    store_bf8(dst + r * APAD + ko, s[0], s[1]);
  }
}

__device__ inline void mfma_step(const unsigned short* As, const unsigned short* Bs,
                                 f32x4 acc[4][4], int wm, int wn, int lane) {
  int r15 = lane & 15, koct = (lane >> 4) * 8;
  short8 a[4], b[4];
#pragma unroll
  for (int mf = 0; mf < 4; mf++)
    a[mf] = *(const short8*)(As + (wm * 64 + mf * 16 + r15) * APAD + koct);
#pragma unroll
  for (int nf = 0; nf < 4; nf++)
    b[nf] = *(const short8*)(Bs + (wn * 64 + nf * 16 + r15) * APAD + koct);
#pragma unroll
  for (int mf = 0; mf < 4; mf++)
#pragma unroll
    for (int nf = 0; nf < 4; nf++)
      acc[mf][nf] = __builtin_amdgcn_mfma_f32_16x16x32_bf16(a[mf], b[nf], acc[mf][nf], 0, 0, 0);
}

// D layout (HW-verified m89): col = lane&15, row = (lane>>4)*4 + j
__device__ inline void mfma_epilogue(float* __restrict__ out, int ldo, int m0, int n0,
                                     int Nmax, const float* __restrict__ bias,
                                     const unsigned char* __restrict__ mask,
                                     const float* __restrict__ base,
                                     f32x4 acc[4][4], int wm, int wn, int lane) {
  int rb = (lane >> 4) * 4, cb = lane & 15;
#pragma unroll
  for (int nf = 0; nf < 4; nf++) {
    int col = n0 + wn * 64 + nf * 16 + cb;
    if (col >= Nmax) continue;
    float bv = bias ? bias[col] : 0.f;
#pragma unroll
    for (int mf = 0; mf < 4; mf++) {
#pragma unroll
      for (int j = 0; j < 4; j++) {
        int row = m0 + wm * 64 + mf * 16 + rb + j;
        float v = acc[mf][nf][j] + bv;
        if (base) v += base[(size_t)row * ldo + col];
        if (mask && mask[row]) v = 0.f;
        out[(size_t)row * ldo + col] = v;
      }
    }
  }
}

__device__ inline void mfma_epilogue_bf16(unsigned short* __restrict__ out, int ldo, int n0,
                                          f32x4 acc[4][4], int wm, int wn, int lane) {
  int rb = (lane >> 4) * 4, cb = lane & 15;
#pragma unroll
  for (int nf = 0; nf < 4; nf++) {
    int col = n0 + wn * 64 + nf * 16 + cb;
#pragma unroll
    for (int mf = 0; mf < 4; mf++) {
#pragma unroll
      for (int j = 0; j < 4; j++) {
        int row = wm * 64 + mf * 16 + rb + j;
        out[(size_t)row * ldo + col] = f2bf(acc[mf][nf][j]);
      }
    }
  }
}

// ---------------- value = enc @ valueW^T + b (masked) ----------------
__global__ __launch_bounds__(256) void k_value_gemm(const float* __restrict__ enc,
    const unsigned short* __restrict__ Wbf, const float* __restrict__ bias,
    const unsigned char* __restrict__ mask, float* __restrict__ out) {
  __shared__ unsigned short As[128 * APAD], Bs[128 * APAD];
  int tid = threadIdx.x;
  int lane = tid & 63, w = tid >> 6, wm = w >> 1, wn = w & 1;
  int m0 = blockIdx.x * 128, n0 = blockIdx.y * 128;
  f32x4 z = {0.f, 0.f, 0.f, 0.f};
  f32x4 acc[4][4];
#pragma unroll
  for (int i = 0; i < 4; i++)
#pragma unroll
    for (int j = 0; j < 4; j++) acc[i][j] = z;
  for (int k0 = 0; k0 < 512; k0 += 32) {
    stage_f32cvt(enc + (size_t)m0 * 512 + k0, 512, As, tid);
    stage_bf(Wbf + (size_t)n0 * 512 + k0, 512, Bs, tid);
    __syncthreads();
    mfma_step(As, Bs, acc, wm, wn, lane);
    __syncthreads();
  }
  mfma_epilogue(out, 512, m0, n0, 512, bias, mask, nullptr, acc, wm, wn, lane);
}

// ---------------- one-time: off_base/aw_base = q @ W[:,512:]^T + b ----------------
__global__ __launch_bounds__(256) void k_qproj(const unsigned short* __restrict__ qbf,
    const unsigned short* __restrict__ offWbf, const float* __restrict__ offb,
    const unsigned short* __restrict__ awWbf, const float* __restrict__ awb,
    float* __restrict__ off_base, float* __restrict__ aw_base) {
  __shared__ unsigned short As[128 * APAD], Bs[128 * APAD];
  const unsigned short* Bw = blockIdx.x ? awWbf : offWbf;
  const float* bias = blockIdx.x ? awb : offb;
  float* out = blockIdx.x ? aw_base : off_base;
  int tid = threadIdx.x;
  int lane = tid & 63, w = tid >> 6, wm = w >> 1, wn = w & 1;
  f32x4 z = {0.f, 0.f, 0.f, 0.f};
  f32x4 acc[4][4];
#pragma unroll
  for (int i = 0; i < 4; i++)
#pragma unroll
    for (int j = 0; j < 4; j++) acc[i][j] = z;
  for (int k0 = 0; k0 < 512; k0 += 32) {
    stage_bf(qbf + k0, 512, As, tid);
    stage_bf(Bw + 512 + k0, 1024, Bs, tid);  // query half: columns 512..1024
    __syncthreads();
    mfma_step(As, Bs, acc, wm, wn, lane);
    __syncthreads();
  }
  mfma_epilogue(out, 128, 0, 0, 128, bias, nullptr, nullptr, acc, wm, wn, lane);
}

// -------- one-time: gates_base[t] = embed(tok_t)@Wih[:,0:512]^T + q@Wih[:,1024:1536]^T ----
__global__ __launch_bounds__(256) void k_gates_pre(const int* __restrict__ seq,
    const float* __restrict__ embedW, const unsigned short* __restrict__ qbf,
    const unsigned short* __restrict__ Wihbf, unsigned short* __restrict__ gates_base) {
  __shared__ unsigned short As[128 * APAD], Bs[128 * APAD];
  __shared__ int tok_s[128];
  int t = blockIdx.y;
  int n0 = blockIdx.x * 128;
  int tid = threadIdx.x;
  if (tid < 128) tok_s[tid] = seq[tid * T_ + t];
  __syncthreads();
  int lane = tid & 63, w = tid >> 6, wm = w >> 1, wn = w & 1;
  f32x4 z = {0.f, 0.f, 0.f, 0.f};
  f32x4 acc[4][4];
#pragma unroll
  for (int i = 0; i < 4; i++)
#pragma unroll
    for (int j = 0; j < 4; j++) acc[i][j] = z;
  for (int k0 = 0; k0 < 1024; k0 += 32) {
    if (k0 < 512) {  // embed gather f32 -> bf16
#pragma unroll
      for (int i = 0; i < 2; i++) {
        int tt = tid + i * 256;
        int r = tt >> 2, ko = (tt & 3) * 8;
        const float4* s = (const float4*)(embedW + (size_t)tok_s[r] * 512 + k0 + ko);
        store_bf8(As + r * APAD + ko, s[0], s[1]);
      }
      stage_bf(Wihbf + (size_t)n0 * 1536 + k0, 1536, Bs, tid);
    } else {
      stage_bf(qbf + (k0 - 512), 512, As, tid);
      stage_bf(Wihbf + (size_t)n0 * 1536 + 1024 + (k0 - 512), 1536, Bs, tid);
    }
    __syncthreads();
    mfma_step(As, Bs, acc, wm, wn, lane);
    __syncthreads();
  }
  mfma_epilogue_bf16(gates_base + (size_t)t * 128 * 2048, 2048, n0, acc, wm, wn, lane);
}

// ---------------- per-step projections: off/aw (h half) + hproj; K=512 ----------------
__global__ __launch_bounds__(256) void k_pre_gemm(const unsigned short* __restrict__ hbf,
    const unsigned short* __restrict__ offWbf, const unsigned short* __restrict__ awWbf,
    const unsigned short* __restrict__ hsWbf, const float* __restrict__ hsb,
    const float* __restrict__ off_base, const float* __restrict__ aw_base,
    float* __restrict__ offo, float* __restrict__ awo, float* __restrict__ hpo) {
  __shared__ unsigned short As[128 * APAD], Bs[128 * APAD];
  int blk = blockIdx.x;
  const unsigned short* Bw; const float* bias; const float* base;
  float* out; int ldkB, n0, ldo;
  if (blk == 0)      { Bw = offWbf; bias = nullptr; base = off_base; out = offo; ldkB = 1024; n0 = 0; ldo = 128; }
  else if (blk == 1) { Bw = awWbf;  bias = nullptr; base = aw_base;  out = awo;  ldkB = 1024; n0 = 0; ldo = 128; }
  else { Bw = hsWbf; bias = hsb; base = nullptr; out = hpo; ldkB = 512; n0 = (blk - 2) * 128; ldo = 512; }
  int tid = threadIdx.x;
  int lane = tid & 63, w = tid >> 6, wm = w >> 1, wn = w & 1;
  f32x4 z = {0.f, 0.f, 0.f, 0.f};
  f32x4 acc[4][4];
#pragma unroll
  for (int i = 0; i < 4; i++)
#pragma unroll
    for (int j = 0; j < 4; j++) acc[i][j] = z;
  for (int k0 = 0; k0 < 512; k0 += 32) {
    stage_bf(hbf + k0, 512, As, tid);
    stage_bf(Bw + (size_t)n0 * ldkB + k0, ldkB, Bs, tid);
    __syncthreads();
    mfma_step(As, Bs, acc, wm, wn, lane);
    __syncthreads();
  }
  mfma_epilogue(out, ldo, 0, n0, ldo, bias, nullptr, base, acc, wm, wn, lane);
}

// ---------------- per-step LSTM gates, split-K: K=1024 over [attn|h], 4 chunks ----------
__global__ __launch_bounds__(256) void k_lstm_gemm(
    const unsigned short* __restrict__ attnbf, const unsigned short* __restrict__ hbf,
    const unsigned short* __restrict__ Wihbf, const unsigned short* __restrict__ Whhbf,
    float* __restrict__ gpart) {
  __shared__ unsigned short As[128 * APAD], Bs[128 * APAD];
  int tid = threadIdx.x;
  int lane = tid & 63, w = tid >> 6, wm = w >> 1, wn = w & 1;
  int n0 = blockIdx.x * 128;
  int kc = blockIdx.y;
  f32x4 z = {0.f, 0.f, 0.f, 0.f};
  f32x4 acc[4][4];
#pragma unroll
  for (int i = 0; i < 4; i++)
#pragma unroll
    for (int j = 0; j < 4; j++) acc[i][j] = z;
  for (int kk = 0; kk < 256; kk += 32) {
    int kg = kc * 256 + kk;
    const unsigned short* Asrc = (kg < 512) ? (attnbf + kg) : (hbf + (kg - 512));
    stage_bf(Asrc, 512, As, tid);
    if (kg < 512) stage_bf(Wihbf + (size_t)n0 * 1536 + 512 + kg, 1536, Bs, tid);
    else          stage_bf(Whhbf + (size_t)n0 * 512 + (kg - 512), 512, Bs, tid);
    __syncthreads();
    mfma_step(As, Bs, acc, wm, wn, lane);
    __syncthreads();
  }
  mfma_epilogue(gpart + (size_t)kc * 128 * 2048, 2048, 0, n0, 2048,
                nullptr, nullptr, nullptr, acc, wm, wn, lane);
}

// ---------------- logits GEMM: M=128, N=12000, K=512 ----------------
__global__ __launch_bounds__(256) void k_logits_gemm(const unsigned short* __restrict__ hbf,
    const unsigned short* __restrict__ Wbf, const float* __restrict__ bias,
    float* __restrict__ out) {
  __shared__ unsigned short As[128 * APAD], Bs[128 * APAD];
  int tid = threadIdx.x;
  int lane = tid & 63, w = tid >> 6, wm = w >> 1, wn = w & 1;
  int n0 = blockIdx.x * 128;
  f32x4 z = {0.f, 0.f, 0.f, 0.f};
  f32x4 acc[4][4];
#pragma unroll
  for (int i = 0; i < 4; i++)
#pragma unroll
    for (int j = 0; j < 4; j++) acc[i][j] = z;
  for (int k0 = 0; k0 < 512; k0 += 32) {
    stage_bf(hbf + k0, 512, As, tid);
#pragma unroll
    for (int i = 0; i < 2; i++) {
      int tt = tid + i * 256;
      int r = tt >> 2, ko = (tt & 3) * 8;
      short8 p = {0, 0, 0, 0, 0, 0, 0, 0};
      if (n0 + r < V_) p = *(const short8*)(Wbf + (size_t)(n0 + r) * 512 + k0 + ko);
      *(short8*)(Bs + r * APAD + ko) = p;
    }
    __syncthreads();
    mfma_step(As, Bs, acc, wm, wn, lane);
    __syncthreads();
  }
  mfma_epilogue(out, V_, 0, n0, V_, bias, nullptr, nullptr, acc, wm, wn, lane);
}

// ---------------- deformable sampling + tanh additive attention ----------------
__global__ __launch_bounds__(256) void k_sample(
    const float* __restrict__ value, const float* __restrict__ offo,
    const float* __restrict__ awo, const float* __restrict__ hproj,
    const float* __restrict__ refp, const float* __restrict__ vrat,
    const float* __restrict__ ctxWT, const float* __restrict__ ctxb,
    const float* __restrict__ alphaW, const float* __restrict__ alphab,
    unsigned short* __restrict__ attnbf) {
  __shared__ float ctx_s[16][HD_];
  __shared__ float aw_s[16];
  __shared__ float wgt_s[16];
  __shared__ float wred[4][16];
  int blk = blockIdx.x;
  int bq = blk >> 3, h = blk & 7;
  int b = bq >> 5;
  int tid = threadIdx.x;
  int lane = tid & 63, wid = tid >> 6;

  if (tid < 16) {
    float v = awo[bq * 128 + h * 16 + tid];
    float m = v;
#pragma unroll
    for (int o = 8; o; o >>= 1) m = fmaxf(m, __shfl_xor(m, o, 16));
    float e = __expf(v - m);
    float s = e;
#pragma unroll
    for (int o = 8; o; o >>= 1) s += __shfl_xor(s, o, 16);
    aw_s[tid] = e / s;
  }
  __syncthreads();

  {
    const int TSv[4] = {2048, 1024, 512, 256};
    const int LSv[4] = {0, 2048, 3072, 3584};
    float ref = refp[bq];
    int hd = tid & 63;
#pragma unroll
    for (int pp = 0; pp < 4; pp++) {
      int p = pp * 4 + (tid >> 6);
      int l = p >> 2;
      int Tl = TSv[l];
      float off = offo[bq * 128 + h * 16 + p];
      float loc = ref * vrat[b * L_ + l] + off / (float)Tl;
      float x = loc * (float)Tl - 0.5f;
      float x0 = floorf(x);
      float wf = x - x0;
      int i0 = (int)x0;
      const float* vb = value + ((size_t)(b * S_ + LSv[l]) * D_) + h * HD_ + hd;
      float v0 = (i0 >= 0 && i0 < Tl) ? vb[(size_t)i0 * D_] : 0.f;
      float v1 = (i0 + 1 >= 0 && i0 + 1 < Tl) ? vb[(size_t)(i0 + 1) * D_] : 0.f;
      ctx_s[p][hd] = (v0 * (1.f - wf) + v1 * wf) * aw_s[p];
    }
  }
  __syncthreads();

  float2 sacc[16];
#pragma unroll
  for (int p = 0; p < 16; p++) { sacc[p].x = 0.f; sacc[p].y = 0.f; }
  for (int k4 = 0; k4 < 16; k4++) {
    float2 wv[4];
#pragma unroll
    for (int kk = 0; kk < 4; kk++)
      wv[kk] = *(const float2*)(ctxWT + (k4 * 4 + kk) * 512 + 2 * tid);
#pragma unroll
    for (int p = 0; p < 16; p++) {
      float4 c = *(const float4*)(&ctx_s[p][k4 * 4]);
      sacc[p].x += c.x * wv[0].x + c.y * wv[1].x + c.z * wv[2].x + c.w * wv[3].x;
      sacc[p].y += c.x * wv[0].y + c.y * wv[1].y + c.z * wv[2].y + c.w * wv[3].y;
    }
  }

  {
    float2 cb = *(const float2*)(ctxb + 2 * tid);
    float2 hp = *(const float2*)(hproj + bq * D_ + 2 * tid);
    float2 al = *(const float2*)(alphaW + 2 * tid);
    float part[16];
#pragma unroll
    for (int p = 0; p < 16; p++)
      part[p] = al.x * fast_tanh(sacc[p].x + cb.x + hp.x) +
                al.y * fast_tanh(sacc[p].y + cb.y + hp.y);
#pragma unroll
    for (int o = 32; o; o >>= 1)
#pragma unroll
      for (int p = 0; p < 16; p++) part[p] += __shfl_xor(part[p], o, 64);
    if (lane == 0)
#pragma unroll
      for (int p = 0; p < 16; p++) wred[wid][p] = part[p];
  }
  __syncthreads();
  if (tid < 16) {
    float v = wred[0][tid] + wred[1][tid] + wred[2][tid] + wred[3][tid] + alphab[0];
    float m = v;
#pragma unroll
    for (int o = 8; o; o >>= 1) m = fmaxf(m, __shfl_xor(m, o, 16));
    float e = __expf(v - m);
    float s = e;
#pragma unroll
    for (int o = 8; o; o >>= 1) s += __shfl_xor(s, o, 16);
    wgt_s[tid] = e / s;
  }
  __syncthreads();
  if (tid < 64) {
    float a = 0.f;
#pragma unroll
    for (int pi = 0; pi < 16; pi++) a += wgt_s[pi] * ctx_s[pi][tid];
    attnbf[bq * D_ + h * HD_ + tid] = f2bf(a);
  }
}

// ---------------- LSTM cell: fused split-K reduce + base add + nonlinearity ----------
__global__ __launch_bounds__(256) void k_cell(const float* __restrict__ gpart,
    const unsigned short* __restrict__ gbase_t,
    const float* __restrict__ c, float* __restrict__ cn, unsigned short* __restrict__ hbf) {
  int idx = blockIdx.x * 256 + threadIdx.x;  // 65536
  int bq = idx >> 9, d = idx & 511;
  size_t row = (size_t)bq * 2048;
  float g4[4];
#pragma unroll
  for (int gate = 0; gate < 4; gate++) {
    size_t off = row + gate * 512 + d;
    float s = bf2f(gbase_t[off]);
    s += gpart[off] + gpart[262144 + off] + gpart[2 * 262144 + off] + gpart[3 * 262144 + off];
    g4[gate] = s;
  }
  float cc = c[idx];
  float c2 = sigmoidf_(g4[1]) * cc + sigmoidf_(g4[0]) * fast_tanh(g4[2]);
  float h2 = sigmoidf_(g4[3]) * fast_tanh(c2);
  cn[idx] = c2;
  hbf[idx] = f2bf(h2);
}

// ---------------- log_softmax rows, write output slice ----------------
__global__ __launch_bounds__(256) void k_lse(const float* __restrict__ logits,
                                             float* __restrict__ out, int t) {
  int row = blockIdx.x, tid = threadIdx.x;
  const float4* lp = (const float4*)(logits + (size_t)row * V_);
  float m = -3.4e38f;
  for (int i = tid; i < V_ / 4; i += 256) {
    float4 v = lp[i];
    m = fmaxf(fmaxf(fmaxf(m, v.x), v.y), fmaxf(v.z, v.w));
  }
  __shared__ float red[4], red2[4];
#pragma unroll
  for (int o = 32; o; o >>= 1) m = fmaxf(m, __shfl_xor(m, o, 64));
  if ((tid & 63) == 0) red[tid >> 6] = m;
  __syncthreads();
  m = fmaxf(fmaxf(red[0], red[1]), fmaxf(red[2], red[3]));
  float s = 0.f;
  for (int i = tid; i < V_ / 4; i += 256) {
    float4 v = lp[i];
    s += __expf(v.x - m) + __expf(v.y - m) + __expf(v.z - m) + __expf(v.w - m);
  }
#pragma unroll
  for (int o = 32; o; o >>= 1) s += __shfl_xor(s, o, 64);
  if ((tid & 63) == 0) red2[tid >> 6] = s;
  __syncthreads();
  s = red2[0] + red2[1] + red2[2] + red2[3];
  float lse = m + __logf(s);
  float4* op = (float4*)(out + ((size_t)row * (T_ - 1) + t) * V_);
  for (int i = tid; i < V_ / 4; i += 256) {
    float4 v = lp[i];
    v.x -= lse; v.y -= lse; v.z -= lse; v.w -= lse;
    op[i] = v;
  }
}

// ---------------- host launch ----------------
extern "C" void kernel_launch(void* const* d_in, const int* in_sizes, int n_in,
                              void* d_out, int out_size, void* d_ws, size_t ws_size,
                              hipStream_t stream) {
  const int* seq             = (const int*)d_in[0];
  const float* query         = (const float*)d_in[1];
  const float* refp          = (const float*)d_in[2];
  const float* enc           = (const float*)d_in[3];
  const float* vrat          = (const float*)d_in[4];
  const unsigned char* mask  = (const unsigned char*)d_in[5];
  const float* embedW        = (const float*)d_in[8];
  const float* logitW        = (const float*)d_in[9];
  const float* logitb        = (const float*)d_in[10];
  const float* Wih           = (const float*)d_in[11];
  const float* Whh           = (const float*)d_in[12];
  const float* valueW        = (const float*)d_in[13];
  const float* valueb        = (const float*)d_in[14];
  const float* offW          = (const float*)d_in[15];
  const float* offb          = (const float*)d_in[16];
  const float* awW           = (const float*)d_in[17];
  const float* awb           = (const float*)d_in[18];
  const float* ctxW          = (const float*)d_in[19];
  const float* ctxb          = (const float*)d_in[20];
  const float* hsW           = (const float*)d_in[21];
  const float* hsb           = (const float*)d_in[22];
  const float* alphaW        = (const float*)d_in[23];
  const float* alphab        = (const float*)d_in[24];

  char* wp = (char*)d_ws;
  auto alloc_f = [&](size_t n) { float* p = (float*)wp; wp += ((n * 4 + 255) / 256) * 256; return p; };
  auto alloc_u = [&](size_t n) { unsigned short* p = (unsigned short*)wp; wp += ((n * 2 + 255) / 256) * 256; return p; };

  float* value   = alloc_f((size_t)B_ * S_ * D_);
  float* logits  = alloc_f((size_t)BQ_ * V_);
  float* gpart   = alloc_f((size_t)4 * BQ_ * 2048);
  float* hproj   = alloc_f((size_t)BQ_ * D_);
  float* offo    = alloc_f((size_t)BQ_ * 128);
  float* awo     = alloc_f((size_t)BQ_ * 128);
  float* off_base= alloc_f((size_t)BQ_ * 128);
  float* aw_base = alloc_f((size_t)BQ_ * 128);
  float* c0      = alloc_f((size_t)BQ_ * D_);
  float* c1      = alloc_f((size_t)BQ_ * D_);
  float* ctxWT   = alloc_f((size_t)64 * 512);
  unsigned short* hbf0    = alloc_u((size_t)BQ_ * D_);
  unsigned short* hbf1    = alloc_u((size_t)BQ_ * D_);
  unsigned short* attnbf  = alloc_u((size_t)BQ_ * D_);
  unsigned short* qbf     = alloc_u((size_t)BQ_ * D_);
  unsigned short* gates_base = alloc_u((size_t)NSTEP * BQ_ * 2048);  // 7.9 MB bf16
  unsigned short* logitWbf = alloc_u((size_t)V_ * D_);
  unsigned short* Wihbf    = alloc_u((size_t)2048 * 1536);
  unsigned short* Whhbf    = alloc_u((size_t)2048 * 512);
  unsigned short* offWbf   = alloc_u((size_t)128 * 1024);
  unsigned short* awWbf    = alloc_u((size_t)128 * 1024);
  unsigned short* hsWbf    = alloc_u((size_t)512 * 512);
  unsigned short* valueWbf = alloc_u((size_t)512 * 512);

  // one-time converts + init
  k_init<<<256, 256, 0, stream>>>(hbf0, c0);
  k_f2bf<<<6000, 256, 0, stream>>>(logitW, logitWbf, 1536000);
  k_f2bf<<<3072, 256, 0, stream>>>(Wih, Wihbf, 786432);
  k_f2bf<<<1024, 256, 0, stream>>>(Whh, Whhbf, 262144);
  k_f2bf<<<128, 256, 0, stream>>>(offW, offWbf, 32768);
  k_f2bf<<<128, 256, 0, stream>>>(awW, awWbf, 32768);
  k_f2bf<<<256, 256, 0, stream>>>(hsW, hsWbf, 65536);
  k_f2bf<<<256, 256, 0, stream>>>(valueW, valueWbf, 65536);
  k_f2bf<<<64, 256, 0, stream>>>(query, qbf, 16384);
  k_transpose_ctxW<<<64, 256, 0, stream>>>(ctxW, ctxWT);

  k_value_gemm<<<dim3(120, 4), 256, 0, stream>>>(enc, valueWbf, valueb, mask, value);
  k_qproj<<<2, 256, 0, stream>>>(qbf, offWbf, offb, awWbf, awb, off_base, aw_base);
  k_gates_pre<<<dim3(16, NSTEP), 256, 0, stream>>>(seq, embedW, qbf, Wihbf, gates_base);

  unsigned short* hb[2] = {hbf0, hbf1};
  float* cb[2] = {c0, c1};
  float* outp = (float*)d_out;

  for (int t = 0; t < NSTEP; t++) {
    int cur = t & 1, nxt = cur ^ 1;
    k_pre_gemm<<<6, 256, 0, stream>>>(hb[cur], offWbf, awWbf, hsWbf, hsb,
                                      off_base, aw_base, offo, awo, hproj);
    k_sample<<<1024, 256, 0, stream>>>(value, offo, awo, hproj, refp, vrat,
                                       ctxWT, ctxb, alphaW, alphab, attnbf);
    k_lstm_gemm<<<dim3(16, 4), 256, 0, stream>>>(attnbf, hb[cur], Wihbf, Whhbf, gpart);
    k_cell<<<256, 256, 0, stream>>>(gpart, gates_base + (size_t)t * BQ_ * 2048,
                                    cb[cur], cb[nxt], hb[nxt]);
    k_logits_gemm<<<94, 256, 0, stream>>>(hb[nxt], logitWbf, logitb, logits);
    k_lse<<<128, 256, 0, stream>>>(logits, outp, t);
  }
}

// Round 4
// 1440.282 us; speedup vs baseline: 3.7267x; 1.0484x over previous
//
#include <hip/hip_runtime.h>

// ---- static problem config ----
#define B_ 4
#define Q_ 32
#define D_ 512
#define H_ 8
#define L_ 4
#define P_ 4
#define V_ 12000
#define T_ 16
#define HD_ 64
#define S_ 3840
#define BQ_ 128
#define NSTEP 15
#define NSLAB 94   // ceil(12000/128)

typedef __attribute__((ext_vector_type(8))) short short8;
typedef __attribute__((ext_vector_type(4))) float f32x4;

__device__ inline unsigned short f2bf(float x) {
  union { float f; unsigned u; } v; v.f = x;
  unsigned u = v.u;
  unsigned r = (u + 0x7fffu + ((u >> 16) & 1u)) >> 16;  // RNE
  return (unsigned short)r;
}
__device__ inline float bf2f(unsigned short b) {
  union { unsigned u; float f; } v; v.u = ((unsigned)b) << 16; return v.f;
}
__device__ inline float fast_tanh(float x) {
  x = fminf(fmaxf(x, -15.f), 15.f);
  float e = __expf(2.f * x);
  return (e - 1.f) / (e + 1.f);
}
__device__ inline float sigmoidf_(float x) { return 1.f / (1.f + __expf(-x)); }

// ---------------- shared-memory union ----------------
#define APAD 40
struct SmemGemm {
  unsigned short As[128 * APAD];
  unsigned short Bs[128 * APAD];
  float mred[128][2];
  float sred[128][2];
  int tok[128];
};
struct SmemSample {
  float ctx_s[16][HD_];
  float aw_s[16];
  float wgt_s[16];
  float wred[4][16];
};
struct SmemOut {
  float ms[NSLAB];
  float ss[NSLAB];
  float lse;
};
union Smem { SmemGemm g; SmemSample s; SmemOut o; };

// ---------------- GEMM common pieces ----------------
__device__ inline void stage_bf(const unsigned short* __restrict__ src, int ldk,
                                unsigned short* dst, int tid) {
#pragma unroll
  for (int i = 0; i < 2; i++) {
    int t = tid + i * 256;
    int r = t >> 2, ko = (t & 3) * 8;
    *(short8*)(dst + r * APAD + ko) = *(const short8*)(src + (size_t)r * ldk + ko);
  }
}

__device__ inline void store_bf8(unsigned short* dst, float4 v0, float4 v1) {
  short8 p;
  p[0] = (short)f2bf(v0.x); p[1] = (short)f2bf(v0.y);
  p[2] = (short)f2bf(v0.z); p[3] = (short)f2bf(v0.w);
  p[4] = (short)f2bf(v1.x); p[5] = (short)f2bf(v1.y);
  p[6] = (short)f2bf(v1.z); p[7] = (short)f2bf(v1.w);
  *(short8*)dst = p;
}

__device__ inline void stage_f32cvt(const float* __restrict__ src, int ldk,
                                    unsigned short* dst, int tid) {
#pragma unroll
  for (int i = 0; i < 2; i++) {
    int t = tid + i * 256;
    int r = t >> 2, ko = (t & 3) * 8;
    const float4* s = (const float4*)(src + (size_t)r * ldk + ko);
    store_bf8(dst + r * APAD + ko, s[0], s[1]);
  }
}

__device__ inline void mfma_step(const unsigned short* As, const unsigned short* Bs,
                                 f32x4 acc[4][4], int wm, int wn, int lane) {
  int r15 = lane & 15, koct = (lane >> 4) * 8;
  short8 a[4], b[4];
#pragma unroll
  for (int mf = 0; mf < 4; mf++)
    a[mf] = *(const short8*)(As + (wm * 64 + mf * 16 + r15) * APAD + koct);
#pragma unroll
  for (int nf = 0; nf < 4; nf++)
    b[nf] = *(const short8*)(Bs + (wn * 64 + nf * 16 + r15) * APAD + koct);
#pragma unroll
  for (int mf = 0; mf < 4; mf++)
#pragma unroll
    for (int nf = 0; nf < 4; nf++)
      acc[mf][nf] = __builtin_amdgcn_mfma_f32_16x16x32_bf16(a[mf], b[nf], acc[mf][nf], 0, 0, 0);
}

// D layout (HW-verified m89): col = lane&15, row = (lane>>4)*4 + j
__device__ inline void mfma_epilogue(float* __restrict__ out, int ldo, int m0, int n0,
                                     int Nmax, const float* __restrict__ bias,
                                     const unsigned char* __restrict__ mask,
                                     const float* __restrict__ base,
                                     f32x4 acc[4][4], int wm, int wn, int lane) {
  int rb = (lane >> 4) * 4, cb = lane & 15;
#pragma unroll
  for (int nf = 0; nf < 4; nf++) {
    int col = n0 + wn * 64 + nf * 16 + cb;
    if (col >= Nmax) continue;
    float bv = bias ? bias[col] : 0.f;
#pragma unroll
    for (int mf = 0; mf < 4; mf++) {
#pragma unroll
      for (int j = 0; j < 4; j++) {
        int row = m0 + wm * 64 + mf * 16 + rb + j;
        float v = acc[mf][nf][j] + bv;
        if (base) v += base[(size_t)row * ldo + col];
        if (mask && mask[row]) v = 0.f;
        out[(size_t)row * ldo + col] = v;
      }
    }
  }
}

__device__ inline void mfma_epilogue_bf16(unsigned short* __restrict__ out, int ldo, int n0,
                                          f32x4 acc[4][4], int wm, int wn, int lane) {
  int rb = (lane >> 4) * 4, cb = lane & 15;
#pragma unroll
  for (int nf = 0; nf < 4; nf++) {
    int col = n0 + wn * 64 + nf * 16 + cb;
#pragma unroll
    for (int mf = 0; mf < 4; mf++) {
#pragma unroll
      for (int j = 0; j < 4; j++) {
        int row = wm * 64 + mf * 16 + rb + j;
        out[(size_t)row * ldo + col] = f2bf(acc[mf][nf][j]);
      }
    }
  }
}

#define ACC_INIT f32x4 acc[4][4]; { f32x4 z = {0.f,0.f,0.f,0.f}; \
  _Pragma("unroll") for (int i_=0;i_<4;i_++) _Pragma("unroll") for (int j_=0;j_<4;j_++) acc[i_][j_]=z; }

// ================= device role functions =================

// ---- value = enc @ valueW^T + b (masked) ----
__device__ void do_value(const float* __restrict__ enc,
    const unsigned short* __restrict__ Wbf, const float* __restrict__ bias,
    const unsigned char* __restrict__ mask, float* __restrict__ out,
    SmemGemm& sm, int m0, int n0) {
  int tid = threadIdx.x;
  int lane = tid & 63, w = tid >> 6, wm = w >> 1, wn = w & 1;
  ACC_INIT;
  for (int k0 = 0; k0 < 512; k0 += 32) {
    stage_f32cvt(enc + (size_t)m0 * 512 + k0, 512, sm.As, tid);
    stage_bf(Wbf + (size_t)n0 * 512 + k0, 512, sm.Bs, tid);
    __syncthreads();
    mfma_step(sm.As, sm.Bs, acc, wm, wn, lane);
    __syncthreads();
  }
  mfma_epilogue(out, 512, m0, n0, 512, bias, mask, nullptr, acc, wm, wn, lane);
}

// ---- off_base/aw_base = q @ W[:,512:]^T + b ----
__device__ void do_qproj(const unsigned short* __restrict__ qbf,
    const unsigned short* __restrict__ Wbf, const float* __restrict__ bias,
    float* __restrict__ out, SmemGemm& sm) {
  int tid = threadIdx.x;
  int lane = tid & 63, w = tid >> 6, wm = w >> 1, wn = w & 1;
  ACC_INIT;
  for (int k0 = 0; k0 < 512; k0 += 32) {
    stage_bf(qbf + k0, 512, sm.As, tid);
    stage_bf(Wbf + 512 + k0, 1024, sm.Bs, tid);
    __syncthreads();
    mfma_step(sm.As, sm.Bs, acc, wm, wn, lane);
    __syncthreads();
  }
  mfma_epilogue(out, 128, 0, 0, 128, bias, nullptr, nullptr, acc, wm, wn, lane);
}

// ---- gates_base[t] = embed(tok_t)@Wih[:,0:512]^T + q@Wih[:,1024:1536]^T ----
__device__ void do_gates_pre(const int* __restrict__ seq,
    const float* __restrict__ embedW, const unsigned short* __restrict__ qbf,
    const unsigned short* __restrict__ Wihbf, unsigned short* __restrict__ gates_base,
    SmemGemm& sm, int t, int n0) {
  int tid = threadIdx.x;
  if (tid < 128) sm.tok[tid] = seq[tid * T_ + t];
  __syncthreads();
  int lane = tid & 63, w = tid >> 6, wm = w >> 1, wn = w & 1;
  ACC_INIT;
  for (int k0 = 0; k0 < 1024; k0 += 32) {
    if (k0 < 512) {
#pragma unroll
      for (int i = 0; i < 2; i++) {
        int tt = tid + i * 256;
        int r = tt >> 2, ko = (tt & 3) * 8;
        const float4* s = (const float4*)(embedW + (size_t)sm.tok[r] * 512 + k0 + ko);
        store_bf8(sm.As + r * APAD + ko, s[0], s[1]);
      }
      stage_bf(Wihbf + (size_t)n0 * 1536 + k0, 1536, sm.Bs, tid);
    } else {
      stage_bf(qbf + (k0 - 512), 512, sm.As, tid);
      stage_bf(Wihbf + (size_t)n0 * 1536 + 1024 + (k0 - 512), 1536, sm.Bs, tid);
    }
    __syncthreads();
    mfma_step(sm.As, sm.Bs, acc, wm, wn, lane);
    __syncthreads();
  }
  mfma_epilogue_bf16(gates_base + (size_t)t * 128 * 2048, 2048, n0, acc, wm, wn, lane);
}

// ---- per-step projections: off/aw (h half) + hproj; K=512 ----
__device__ void do_pre(const unsigned short* __restrict__ hbf,
    const unsigned short* __restrict__ offWbf, const unsigned short* __restrict__ awWbf,
    const unsigned short* __restrict__ hsWbf, const float* __restrict__ hsb,
    const float* __restrict__ off_base, const float* __restrict__ aw_base,
    float* __restrict__ offo, float* __restrict__ awo, float* __restrict__ hpo,
    SmemGemm& sm, int blk) {
  const unsigned short* Bw; const float* bias; const float* base;
  float* out; int ldkB, n0, ldo;
  if (blk == 0)      { Bw = offWbf; bias = nullptr; base = off_base; out = offo; ldkB = 1024; n0 = 0; ldo = 128; }
  else if (blk == 1) { Bw = awWbf;  bias = nullptr; base = aw_base;  out = awo;  ldkB = 1024; n0 = 0; ldo = 128; }
  else { Bw = hsWbf; bias = hsb; base = nullptr; out = hpo; ldkB = 512; n0 = (blk - 2) * 128; ldo = 512; }
  int tid = threadIdx.x;
  int lane = tid & 63, w = tid >> 6, wm = w >> 1, wn = w & 1;
  ACC_INIT;
  for (int k0 = 0; k0 < 512; k0 += 32) {
    stage_bf(hbf + k0, 512, sm.As, tid);
    stage_bf(Bw + (size_t)n0 * ldkB + k0, ldkB, sm.Bs, tid);
    __syncthreads();
    mfma_step(sm.As, sm.Bs, acc, wm, wn, lane);
    __syncthreads();
  }
  mfma_epilogue(out, ldo, 0, n0, ldo, bias, nullptr, base, acc, wm, wn, lane);
}

// ---- logits slab GEMM + per-slab (max, expsum) partials ----
__device__ void do_logits_lse(const unsigned short* __restrict__ hbf,
    const unsigned short* __restrict__ Wbf, const float* __restrict__ bias,
    float* __restrict__ logits, float* __restrict__ m_sb, float* __restrict__ s_sb,
    SmemGemm& sm, int slab) {
  int tid = threadIdx.x;
  int lane = tid & 63, w = tid >> 6, wm = w >> 1, wn = w & 1;
  int n0 = slab * 128;
  ACC_INIT;
  for (int k0 = 0; k0 < 512; k0 += 32) {
    stage_bf(hbf + k0, 512, sm.As, tid);
#pragma unroll
    for (int i = 0; i < 2; i++) {
      int tt = tid + i * 256;
      int r = tt >> 2, ko = (tt & 3) * 8;
      short8 p = {0, 0, 0, 0, 0, 0, 0, 0};
      if (n0 + r < V_) p = *(const short8*)(Wbf + (size_t)(n0 + r) * 512 + k0 + ko);
      *(short8*)(sm.Bs + r * APAD + ko) = p;
    }
    __syncthreads();
    mfma_step(sm.As, sm.Bs, acc, wm, wn, lane);
    __syncthreads();
  }
  // epilogue: store logits + per-row slab (max, expsum)
  int rb = (lane >> 4) * 4, cb = lane & 15;
#pragma unroll
  for (int mf = 0; mf < 4; mf++) {
#pragma unroll
    for (int j = 0; j < 4; j++) {
      int row = wm * 64 + mf * 16 + rb + j;
      float vv[4];
      float mx = -3.4e38f;
#pragma unroll
      for (int nf = 0; nf < 4; nf++) {
        int col = n0 + wn * 64 + nf * 16 + cb;
        bool ok = col < V_;
        float v = acc[mf][nf][j] + (ok ? bias[col] : 0.f);
        if (ok) logits[(size_t)row * V_ + col] = v;
        vv[nf] = ok ? v : -3.4e38f;
        mx = fmaxf(mx, vv[nf]);
      }
#pragma unroll
      for (int o = 8; o; o >>= 1) mx = fmaxf(mx, __shfl_xor(mx, o, 16));
      float sme = 0.f;
#pragma unroll
      for (int nf = 0; nf < 4; nf++) sme += (vv[nf] > -3.0e38f) ? __expf(vv[nf] - mx) : 0.f;
#pragma unroll
      for (int o = 8; o; o >>= 1) sme += __shfl_xor(sme, o, 16);
      if (cb == 0) { sm.mred[row][wn] = mx; sm.sred[row][wn] = sme; }
    }
  }
  __syncthreads();
  if (tid < 128) {
    float m0 = sm.mred[tid][0], m1 = sm.mred[tid][1];
    float M = fmaxf(m0, m1);
    float S = sm.sred[tid][0] * __expf(m0 - M) + sm.sred[tid][1] * __expf(m1 - M);
    m_sb[tid * 96 + slab] = M;
    s_sb[tid * 96 + slab] = S;
  }
}

// ---- combine slab partials -> lse; write out = logits - lse ----
__device__ void do_out(const float* __restrict__ logits, const float* __restrict__ m_sb,
                       const float* __restrict__ s_sb, float* __restrict__ outp, int t,
                       int row, SmemOut& sm) {
  int tid = threadIdx.x;
  if (tid < NSLAB) { sm.ms[tid] = m_sb[row * 96 + tid]; sm.ss[tid] = s_sb[row * 96 + tid]; }
  __syncthreads();
  if (tid < 64) {
    float m = -3.4e38f, s = 0.f;
    for (int i = tid; i < NSLAB; i += 64) {
      float mi = sm.ms[i], si = sm.ss[i];
      float M = fmaxf(m, mi);
      s = s * __expf(m - M) + si * __expf(mi - M);
      m = M;
    }
#pragma unroll
    for (int o = 32; o; o >>= 1) {
      float mo = __shfl_xor(m, o, 64), so = __shfl_xor(s, o, 64);
      float M = fmaxf(m, mo);
      s = s * __expf(m - M) + so * __expf(mo - M);
      m = M;
    }
    if (tid == 0) sm.lse = m + __logf(s);
  }
  __syncthreads();
  float lse = sm.lse;
  const float4* lp = (const float4*)(logits + (size_t)row * V_);
  float4* op = (float4*)(outp + ((size_t)row * (T_ - 1) + t) * V_);
  for (int i = tid; i < V_ / 4; i += 256) {
    float4 v = lp[i];
    v.x -= lse; v.y -= lse; v.z -= lse; v.w -= lse;
    op[i] = v;
  }
}

// ---- deformable sampling + tanh additive attention ----
__device__ void do_sample(const float* __restrict__ value, const float* __restrict__ offo,
    const float* __restrict__ awo, const float* __restrict__ hproj,
    const float* __restrict__ refp, const float* __restrict__ vrat,
    const float* __restrict__ ctxWT, const float* __restrict__ ctxb,
    const float* __restrict__ alphaW, const float* __restrict__ alphab,
    unsigned short* __restrict__ attnbf, int blk, SmemSample& sm) {
  int bq = blk >> 3, h = blk & 7;
  int b = bq >> 5;
  int tid = threadIdx.x;
  int lane = tid & 63, wid = tid >> 6;

  if (tid < 16) {
    float v = awo[bq * 128 + h * 16 + tid];
    float m = v;
#pragma unroll
    for (int o = 8; o; o >>= 1) m = fmaxf(m, __shfl_xor(m, o, 16));
    float e = __expf(v - m);
    float s = e;
#pragma unroll
    for (int o = 8; o; o >>= 1) s += __shfl_xor(s, o, 16);
    sm.aw_s[tid] = e / s;
  }
  __syncthreads();

  {
    const int TSv[4] = {2048, 1024, 512, 256};
    const int LSv[4] = {0, 2048, 3072, 3584};
    float ref = refp[bq];
    int hd = tid & 63;
#pragma unroll
    for (int pp = 0; pp < 4; pp++) {
      int p = pp * 4 + (tid >> 6);
      int l = p >> 2;
      int Tl = TSv[l];
      float off = offo[bq * 128 + h * 16 + p];
      float loc = ref * vrat[b * L_ + l] + off / (float)Tl;
      float x = loc * (float)Tl - 0.5f;
      float x0 = floorf(x);
      float wf = x - x0;
      int i0 = (int)x0;
      const float* vb = value + ((size_t)(b * S_ + LSv[l]) * D_) + h * HD_ + hd;
      float v0 = (i0 >= 0 && i0 < Tl) ? vb[(size_t)i0 * D_] : 0.f;
      float v1 = (i0 + 1 >= 0 && i0 + 1 < Tl) ? vb[(size_t)(i0 + 1) * D_] : 0.f;
      sm.ctx_s[p][hd] = (v0 * (1.f - wf) + v1 * wf) * sm.aw_s[p];
    }
  }
  __syncthreads();

  float2 sacc[16];
#pragma unroll
  for (int p = 0; p < 16; p++) { sacc[p].x = 0.f; sacc[p].y = 0.f; }
  for (int k4 = 0; k4 < 16; k4++) {
    float2 wv[4];
#pragma unroll
    for (int kk = 0; kk < 4; kk++)
      wv[kk] = *(const float2*)(ctxWT + (k4 * 4 + kk) * 512 + 2 * tid);
#pragma unroll
    for (int p = 0; p < 16; p++) {
      float4 c = *(const float4*)(&sm.ctx_s[p][k4 * 4]);
      sacc[p].x += c.x * wv[0].x + c.y * wv[1].x + c.z * wv[2].x + c.w * wv[3].x;
      sacc[p].y += c.x * wv[0].y + c.y * wv[1].y + c.z * wv[2].y + c.w * wv[3].y;
    }
  }

  {
    float2 cb = *(const float2*)(ctxb + 2 * tid);
    float2 hp = *(const float2*)(hproj + bq * D_ + 2 * tid);
    float2 al = *(const float2*)(alphaW + 2 * tid);
    float part[16];
#pragma unroll
    for (int p = 0; p < 16; p++)
      part[p] = al.x * fast_tanh(sacc[p].x + cb.x + hp.x) +
                al.y * fast_tanh(sacc[p].y + cb.y + hp.y);
#pragma unroll
    for (int o = 32; o; o >>= 1)
#pragma unroll
      for (int p = 0; p < 16; p++) part[p] += __shfl_xor(part[p], o, 64);
    if (lane == 0)
#pragma unroll
      for (int p = 0; p < 16; p++) sm.wred[wid][p] = part[p];
  }
  __syncthreads();
  if (tid < 16) {
    float v = sm.wred[0][tid] + sm.wred[1][tid] + sm.wred[2][tid] + sm.wred[3][tid] + alphab[0];
    float m = v;
#pragma unroll
    for (int o = 8; o; o >>= 1) m = fmaxf(m, __shfl_xor(m, o, 16));
    float e = __expf(v - m);
    float s = e;
#pragma unroll
    for (int o = 8; o; o >>= 1) s += __shfl_xor(s, o, 16);
    sm.wgt_s[tid] = e / s;
  }
  __syncthreads();
  if (tid < 64) {
    float a = 0.f;
#pragma unroll
    for (int pi = 0; pi < 16; pi++) a += sm.wgt_s[pi] * sm.ctx_s[pi][tid];
    attnbf[bq * D_ + h * HD_ + tid] = f2bf(a);
  }
}

// ================= kernels =================

// one-time: all weight converts + h0/c0 init + ctxW transpose in one launch
__global__ __launch_bounds__(256) void k_prep(const float* __restrict__ logitW,
    const float* __restrict__ Wih, const float* __restrict__ Whh,
    const float* __restrict__ offW, const float* __restrict__ awW,
    const float* __restrict__ hsW, const float* __restrict__ valueW,
    const float* __restrict__ query, const float* __restrict__ ctxW,
    unsigned short* __restrict__ logitWbf, unsigned short* __restrict__ Wihbf,
    unsigned short* __restrict__ Whhbf, unsigned short* __restrict__ offWbf,
    unsigned short* __restrict__ awWbf, unsigned short* __restrict__ hsWbf,
    unsigned short* __restrict__ valueWbf, unsigned short* __restrict__ qbf,
    float* __restrict__ ctxWT, unsigned short* __restrict__ hbf0, float* __restrict__ c0) {
  int gi = blockIdx.x * 256 + threadIdx.x;  // float4-granular index
  const int e0 = 1536000, e1 = e0 + 786432, e2 = e1 + 262144, e3 = e2 + 32768,
            e4 = e3 + 32768, e5 = e4 + 65536, e6 = e5 + 65536, e7 = e6 + 16384;
  if (gi < e7) {
    const float* src; unsigned short* dst; int lo;
    if (gi < e0)      { src = logitW; dst = logitWbf; lo = gi; }
    else if (gi < e1) { src = Wih;    dst = Wihbf;    lo = gi - e0; }
    else if (gi < e2) { src = Whh;    dst = Whhbf;    lo = gi - e1; }
    else if (gi < e3) { src = offW;   dst = offWbf;   lo = gi - e2; }
    else if (gi < e4) { src = awW;    dst = awWbf;    lo = gi - e3; }
    else if (gi < e5) { src = hsW;    dst = hsWbf;    lo = gi - e4; }
    else if (gi < e6) { src = valueW; dst = valueWbf; lo = gi - e5; }
    else              { src = query;  dst = qbf;      lo = gi - e6; }
    float4 v = ((const float4*)src)[lo];
    ushort4 o;
    o.x = f2bf(v.x); o.y = f2bf(v.y); o.z = f2bf(v.z); o.w = f2bf(v.w);
    ((ushort4*)dst)[lo] = o;
  } else if (gi < e7 + 16384) {
    int i = gi - e7;
    ushort4 z4; z4.x = 0; z4.y = 0; z4.z = 0; z4.w = 0;
    ((ushort4*)hbf0)[i] = z4;
    float4 z = {0.f, 0.f, 0.f, 0.f};
    ((float4*)c0)[i] = z;
  } else if (gi < e7 + 16384 + 8192) {
    int i = gi - e7 - 16384;
    int k = i >> 7, d4 = i & 127;
    float4 o;
    o.x = ctxW[(d4 * 4 + 0) * 64 + k];
    o.y = ctxW[(d4 * 4 + 1) * 64 + k];
    o.z = ctxW[(d4 * 4 + 2) * 64 + k];
    o.w = ctxW[(d4 * 4 + 3) * 64 + k];
    ((float4*)ctxWT)[k * 128 + d4] = o;
  }
}

// one-time GEMMs: value (480 blocks) + qproj (2) + gates_pre (240)
__global__ __launch_bounds__(256) void k_onetime(const float* __restrict__ enc,
    const unsigned short* __restrict__ valueWbf, const float* __restrict__ valueb,
    const unsigned char* __restrict__ mask, float* __restrict__ value,
    const unsigned short* __restrict__ qbf,
    const unsigned short* __restrict__ offWbf, const float* __restrict__ offb,
    const unsigned short* __restrict__ awWbf, const float* __restrict__ awb,
    float* __restrict__ off_base, float* __restrict__ aw_base,
    const int* __restrict__ seq, const float* __restrict__ embedW,
    const unsigned short* __restrict__ Wihbf, unsigned short* __restrict__ gates_base) {
  __shared__ Smem sm;
  int blk = blockIdx.x;
  if (blk < 480) {
    do_value(enc, valueWbf, valueb, mask, value, sm.g, (blk >> 2) * 128, (blk & 3) * 128);
  } else if (blk < 482) {
    if (blk == 480) do_qproj(qbf, offWbf, offb, off_base, sm.g);
    else            do_qproj(qbf, awWbf, awb, aw_base, sm.g);
  } else {
    int g = blk - 482;
    do_gates_pre(seq, embedW, qbf, Wihbf, gates_base, sm.g, g >> 4, (g & 15) * 128);
  }
}

// standalone pre (t=0)
__global__ __launch_bounds__(256) void k_pre(const unsigned short* __restrict__ hbf,
    const unsigned short* __restrict__ offWbf, const unsigned short* __restrict__ awWbf,
    const unsigned short* __restrict__ hsWbf, const float* __restrict__ hsb,
    const float* __restrict__ off_base, const float* __restrict__ aw_base,
    float* __restrict__ offo, float* __restrict__ awo, float* __restrict__ hpo) {
  __shared__ Smem sm;
  do_pre(hbf, offWbf, awWbf, hsWbf, hsb, off_base, aw_base, offo, awo, hpo, sm.g, blockIdx.x);
}

// standalone sample (t=0)
__global__ __launch_bounds__(256) void k_sample0(const float* __restrict__ value,
    const float* __restrict__ offo, const float* __restrict__ awo,
    const float* __restrict__ hproj, const float* __restrict__ refp,
    const float* __restrict__ vrat, const float* __restrict__ ctxWT,
    const float* __restrict__ ctxb, const float* __restrict__ alphaW,
    const float* __restrict__ alphab, unsigned short* __restrict__ attnbf) {
  __shared__ Smem sm;
  do_sample(value, offo, awo, hproj, refp, vrat, ctxWT, ctxb, alphaW, alphab, attnbf,
            blockIdx.x, sm.s);
}

// per-step LSTM gates, split-K: K=1024 over [attn|h], 4 chunks
__global__ __launch_bounds__(256) void k_lstm_gemm(
    const unsigned short* __restrict__ attnbf, const unsigned short* __restrict__ hbf,
    const unsigned short* __restrict__ Wihbf, const unsigned short* __restrict__ Whhbf,
    float* __restrict__ gpart) {
  __shared__ Smem smu;
  SmemGemm& sm = smu.g;
  int tid = threadIdx.x;
  int lane = tid & 63, w = tid >> 6, wm = w >> 1, wn = w & 1;
  int n0 = blockIdx.x * 128;
  int kc = blockIdx.y;
  ACC_INIT;
  for (int kk = 0; kk < 256; kk += 32) {
    int kg = kc * 256 + kk;
    const unsigned short* Asrc = (kg < 512) ? (attnbf + kg) : (hbf + (kg - 512));
    stage_bf(Asrc, 512, sm.As, tid);
    if (kg < 512) stage_bf(Wihbf + (size_t)n0 * 1536 + 512 + kg, 1536, sm.Bs, tid);
    else          stage_bf(Whhbf + (size_t)n0 * 512 + (kg - 512), 512, sm.Bs, tid);
    __syncthreads();
    mfma_step(sm.As, sm.Bs, acc, wm, wn, lane);
    __syncthreads();
  }
  mfma_epilogue(gpart + (size_t)kc * 128 * 2048, 2048, 0, n0, 2048,
                nullptr, nullptr, nullptr, acc, wm, wn, lane);
}

// LSTM cell: fused split-K reduce + base add + nonlinearity
__global__ __launch_bounds__(256) void k_cell(const float* __restrict__ gpart,
    const unsigned short* __restrict__ gbase_t,
    const float* __restrict__ c, float* __restrict__ cn, unsigned short* __restrict__ hbf) {
  int idx = blockIdx.x * 256 + threadIdx.x;  // 65536
  int bq = idx >> 9, d = idx & 511;
  size_t row = (size_t)bq * 2048;
  float g4[4];
#pragma unroll
  for (int gate = 0; gate < 4; gate++) {
    size_t off = row + gate * 512 + d;
    float s = bf2f(gbase_t[off]);
    s += gpart[off] + gpart[262144 + off] + gpart[2 * 262144 + off] + gpart[3 * 262144 + off];
    g4[gate] = s;
  }
  float cc = c[idx];
  float c2 = sigmoidf_(g4[1]) * cc + sigmoidf_(g4[0]) * fast_tanh(g4[2]);
  float h2 = sigmoidf_(g4[3]) * fast_tanh(c2);
  cn[idx] = c2;
  hbf[idx] = f2bf(h2);
}

// merged: logits(t) [94 blocks] + pre(t+1) [6 blocks], both read h_{t+1}
__global__ __launch_bounds__(256) void k_logits_pre(const unsigned short* __restrict__ hnew,
    const unsigned short* __restrict__ logitWbf, const float* __restrict__ logitb,
    float* __restrict__ logits, float* __restrict__ m_sb, float* __restrict__ s_sb,
    const unsigned short* __restrict__ offWbf, const unsigned short* __restrict__ awWbf,
    const unsigned short* __restrict__ hsWbf, const float* __restrict__ hsb,
    const float* __restrict__ off_base, const float* __restrict__ aw_base,
    float* __restrict__ offo, float* __restrict__ awo, float* __restrict__ hpo) {
  __shared__ Smem sm;
  int blk = blockIdx.x;
  if (blk < NSLAB)
    do_logits_lse(hnew, logitWbf, logitb, logits, m_sb, s_sb, sm.g, blk);
  else
    do_pre(hnew, offWbf, awWbf, hsWbf, hsb, off_base, aw_base, offo, awo, hpo,
           sm.g, blk - NSLAB);
}

// merged: out(t) [128 blocks] + sample(t+1) [1024 blocks]
__global__ __launch_bounds__(256) void k_out_sample(const float* __restrict__ logits,
    const float* __restrict__ m_sb, const float* __restrict__ s_sb,
    float* __restrict__ outp, int t,
    const float* __restrict__ value, const float* __restrict__ offo,
    const float* __restrict__ awo, const float* __restrict__ hproj,
    const float* __restrict__ refp, const float* __restrict__ vrat,
    const float* __restrict__ ctxWT, const float* __restrict__ ctxb,
    const float* __restrict__ alphaW, const float* __restrict__ alphab,
    unsigned short* __restrict__ attnbf) {
  __shared__ Smem sm;
  int blk = blockIdx.x;
  if (blk < 128)
    do_out(logits, m_sb, s_sb, outp, t, blk, sm.o);
  else
    do_sample(value, offo, awo, hproj, refp, vrat, ctxWT, ctxb, alphaW, alphab, attnbf,
              blk - 128, sm.s);
}

// ---------------- host launch ----------------
extern "C" void kernel_launch(void* const* d_in, const int* in_sizes, int n_in,
                              void* d_out, int out_size, void* d_ws, size_t ws_size,
                              hipStream_t stream) {
  const int* seq             = (const int*)d_in[0];
  const float* query         = (const float*)d_in[1];
  const float* refp          = (const float*)d_in[2];
  const float* enc           = (const float*)d_in[3];
  const float* vrat          = (const float*)d_in[4];
  const unsigned char* mask  = (const unsigned char*)d_in[5];
  const float* embedW        = (const float*)d_in[8];
  const float* logitW        = (const float*)d_in[9];
  const float* logitb        = (const float*)d_in[10];
  const float* Wih           = (const float*)d_in[11];
  const float* Whh           = (const float*)d_in[12];
  const float* valueW        = (const float*)d_in[13];
  const float* valueb        = (const float*)d_in[14];
  const float* offW          = (const float*)d_in[15];
  const float* offb          = (const float*)d_in[16];
  const float* awW           = (const float*)d_in[17];
  const float* awb           = (const float*)d_in[18];
  const float* ctxW          = (const float*)d_in[19];
  const float* ctxb          = (const float*)d_in[20];
  const float* hsW           = (const float*)d_in[21];
  const float* hsb           = (const float*)d_in[22];
  const float* alphaW        = (const float*)d_in[23];
  const float* alphab        = (const float*)d_in[24];

  char* wp = (char*)d_ws;
  auto alloc_f = [&](size_t n) { float* p = (float*)wp; wp += ((n * 4 + 255) / 256) * 256; return p; };
  auto alloc_u = [&](size_t n) { unsigned short* p = (unsigned short*)wp; wp += ((n * 2 + 255) / 256) * 256; return p; };

  float* value   = alloc_f((size_t)B_ * S_ * D_);
  float* logits  = alloc_f((size_t)BQ_ * V_);
  float* gpart   = alloc_f((size_t)4 * BQ_ * 2048);
  float* hproj   = alloc_f((size_t)BQ_ * D_);
  float* offo    = alloc_f((size_t)BQ_ * 128);
  float* awo     = alloc_f((size_t)BQ_ * 128);
  float* off_base= alloc_f((size_t)BQ_ * 128);
  float* aw_base = alloc_f((size_t)BQ_ * 128);
  float* c0      = alloc_f((size_t)BQ_ * D_);
  float* c1      = alloc_f((size_t)BQ_ * D_);
  float* ctxWT   = alloc_f((size_t)64 * 512);
  float* m_sb    = alloc_f((size_t)BQ_ * 96);
  float* s_sb    = alloc_f((size_t)BQ_ * 96);
  unsigned short* hbf0    = alloc_u((size_t)BQ_ * D_);
  unsigned short* hbf1    = alloc_u((size_t)BQ_ * D_);
  unsigned short* attnbf  = alloc_u((size_t)BQ_ * D_);
  unsigned short* qbf     = alloc_u((size_t)BQ_ * D_);
  unsigned short* gates_base = alloc_u((size_t)NSTEP * BQ_ * 2048);
  unsigned short* logitWbf = alloc_u((size_t)V_ * D_);
  unsigned short* Wihbf    = alloc_u((size_t)2048 * 1536);
  unsigned short* Whhbf    = alloc_u((size_t)2048 * 512);
  unsigned short* offWbf   = alloc_u((size_t)128 * 1024);
  unsigned short* awWbf    = alloc_u((size_t)128 * 1024);
  unsigned short* hsWbf    = alloc_u((size_t)512 * 512);
  unsigned short* valueWbf = alloc_u((size_t)512 * 512);

  // one-time: converts + init + transpose (1 launch), then parallel GEMMs (1 launch)
  k_prep<<<11024, 256, 0, stream>>>(logitW, Wih, Whh, offW, awW, hsW, valueW, query, ctxW,
                                    logitWbf, Wihbf, Whhbf, offWbf, awWbf, hsWbf,
                                    valueWbf, qbf, ctxWT, hbf0, c0);
  k_onetime<<<722, 256, 0, stream>>>(enc, valueWbf, valueb, mask, value,
                                     qbf, offWbf, offb, awWbf, awb, off_base, aw_base,
                                     seq, embedW, Wihbf, gates_base);

  unsigned short* hb[2] = {hbf0, hbf1};
  float* cb[2] = {c0, c1};
  float* outp = (float*)d_out;

  // t=0 prologue: pre(0) + sample(0) from h0
  k_pre<<<6, 256, 0, stream>>>(hb[0], offWbf, awWbf, hsWbf, hsb,
                               off_base, aw_base, offo, awo, hproj);
  k_sample0<<<1024, 256, 0, stream>>>(value, offo, awo, hproj, refp, vrat,
                                      ctxWT, ctxb, alphaW, alphab, attnbf);

  for (int t = 0; t < NSTEP; t++) {
    int cur = t & 1, nxt = cur ^ 1;
    k_lstm_gemm<<<dim3(16, 4), 256, 0, stream>>>(attnbf, hb[cur], Wihbf, Whhbf, gpart);
    k_cell<<<256, 256, 0, stream>>>(gpart, gates_base + (size_t)t * BQ_ * 2048,
                                    cb[cur], cb[nxt], hb[nxt]);
    // logits(t) from h_{t+1}  +  pre(t+1) from h_{t+1}
    k_logits_pre<<<NSLAB + 6, 256, 0, stream>>>(hb[nxt], logitWbf, logitb,
                                                logits, m_sb, s_sb,
                                                offWbf, awWbf, hsWbf, hsb,
                                                off_base, aw_base, offo, awo, hproj);
    // out(t)  +  sample(t+1)
    k_out_sample<<<128 + 1024, 256, 0, stream>>>(logits, m_sb, s_sb, outp, t,
                                                 value, offo, awo, hproj, refp, vrat,
                                                 ctxWT, ctxb, alphaW, alphab, attnbf);
  }
}